// Round 9
// baseline (332.006 us; speedup 1.0000x reference)
//
#include <hip/hip_runtime.h>
#include <hip/hip_fp16.h>
#include <math.h>

#define BB 2
#define CC 64
#define NN 16384
#define DD 3
#define KK 128
#define EE 262144
#define GG 3
#define PP 128           // n-chunks for spectral-forward partials
#define LL (NN/PP)       // 128 n per chunk
#define KTOT 576         // concat K: 256 interleaved cos/sin + 64 x + 64 h + 192 gradf

// ---- workspace layout (float elements) ----
constexpr size_t OFF_XT   = 0;                                  // xT[b][n][i]
constexpr size_t OFF_PC   = OFF_XT   + (size_t)BB*NN*CC;        // partial A_c
constexpr size_t OFF_PS   = OFF_PC   + (size_t)BB*PP*CC*KK;     // partial A_s
constexpr size_t OFF_BIN4 = OFF_PC;                             // float4 binlist[b][E] (aliases pc/ps)
constexpr size_t OFF_AC   = OFF_PS   + (size_t)BB*PP*CC*KK;     // A_c[b][i][k]
constexpr size_t OFF_AS   = OFF_AC   + (size_t)BB*CC*KK;
constexpr size_t OFF_FTC  = OFF_AS   + (size_t)BB*CC*KK;        // 2*f_c[b][k][o]
constexpr size_t OFF_FTS  = OFF_FTC  + (size_t)BB*KK*CC;        // 2*f_s[b][k][o]
constexpr size_t OFF_F0   = OFF_FTS  + (size_t)BB*KK*CC;        // f0[b][o]
constexpr size_t OFF_X0   = OFF_F0   + (size_t)BB*CC;           // x0[b][i]
constexpr size_t OFF_CNT  = OFF_X0   + (size_t)BB*CC;           // int counts (zeroed)
constexpr size_t OFF_OFFS = OFF_CNT  + (size_t)BB*NN;           // int offsets
constexpr size_t OFF_CUR  = OFF_OFFS + (size_t)BB*NN;           // int cursor
constexpr size_t OFF_GRT  = OFF_CUR  + (size_t)BB*NN;           // gradfT[b][g][n]
constexpr size_t OFF_APAN = OFF_GRT  + (size_t)BB*192*NN;       // Apan[b][576][64]
constexpr size_t OFF_WT   = OFF_APAN + (size_t)BB*KTOT*CC;      // W^T  [j][o]
constexpr size_t OFF_WXT  = OFF_WT   + (size_t)CC*CC;           // wx^T [j][i]
constexpr size_t OFF_W2T  = OFF_WXT  + (size_t)CC*CC;           // w2^T [i][o]
constexpr size_t OFF_GWT  = OFF_W2T  + (size_t)CC*CC;           // gw^T [g][o]
constexpr size_t OFF_GWXT = OFF_GWT  + (size_t)CC*CC*DD;        // geo_wx^T [g][i]

// ---- small transposes ----
__global__ void k_prep(const float* __restrict__ W, const float* __restrict__ gw,
                       const float* __restrict__ geo_wx, const float* __restrict__ wx,
                       const float* __restrict__ w2,
                       float* WT, float* wxT, float* w2T, float* gwT, float* gwxT) {
    int idx = blockIdx.x*256 + threadIdx.x;
    if (idx < CC*CC) { int j = idx>>6, o = idx&63; WT[idx]  = W[o*CC+j];  }
    if (idx < CC*CC) { int j = idx>>6, i = idx&63; wxT[idx] = wx[i*CC+j]; }
    if (idx < CC*CC) { int i = idx>>6, o = idx&63; w2T[idx] = w2[o*CC+i]; }
    if (idx < CC*CC*DD) { int g = idx>>6, o = idx&63; gwT[idx] = gw[o*(CC*DD)+g]; }
    if (idx < GG*CC) { int g = idx>>6, i = idx&63; gwxT[idx] = geo_wx[i*GG+g]; }
}

// ---- fused pre-pass: transpose x -> xT, x0 reduction, edge-count ----
// blocks 0..511: transpose; 512..639: x0; 640..2687: count
__global__ void __launch_bounds__(256) k_pre(const float* __restrict__ x,
                                             const float* __restrict__ nwt,
                                             const int* __restrict__ edges,
                                             float* __restrict__ xT,
                                             float* __restrict__ x0,
                                             int* __restrict__ counts) {
    int blk = blockIdx.x;
    int tid = threadIdx.x;
    __shared__ float tile[64][65];
    __shared__ float red[256];
    if (blk < BB*(NN/64)) {
        int b = blk / (NN/64);
        int n0 = (blk % (NN/64)) * 64;
        int c = tid & 63, r4 = tid >> 6;
        for (int rr = 0; rr < 16; rr++) {
            int i = r4*16 + rr;
            tile[i][c] = x[((size_t)b*CC + i)*NN + n0 + c];
        }
        __syncthreads();
        for (int rr = 0; rr < 16; rr++) {
            int nn = r4*16 + rr;
            xT[((size_t)b*NN + n0 + nn)*CC + c] = tile[c][nn];
        }
    } else if (blk < BB*(NN/64) + BB*CC) {
        int bi = blk - BB*(NN/64);
        int b = bi >> 6, i = bi & 63;
        const float4* __restrict__ xr = (const float4*)&x[((size_t)b*CC + i)*NN];
        const float4* __restrict__ wr = (const float4*)&nwt[(size_t)b*NN];
        float s = 0.f;
        for (int t = tid; t < NN/4; t += 256) {
            float4 xv = xr[t];
            float4 wv = wr[t];
            s += xv.x*wv.x + xv.y*wv.y + xv.z*wv.z + xv.w*wv.w;
        }
        red[tid] = s;
        __syncthreads();
        for (int off = 128; off > 0; off >>= 1) {
            if (tid < off) red[tid] += red[tid+off];
            __syncthreads();
        }
        if (tid == 0) x0[b*CC + i] = red[0];
    } else {
        int idx = (blk - (BB*(NN/64) + BB*CC))*256 + tid;
        if (idx < BB*EE) {
            int tgt = edges[(size_t)idx*2 + 0];
            int b = idx / EE;
            atomicAdd(&counts[b*NN + tgt], 1);
        }
    }
}

// ---- spectral forward partials: A_c/A_s[b][i][k] over n-chunks ----
__global__ void __launch_bounds__(256) k_a(const float* __restrict__ xT,
                                           const float* __restrict__ nodes,
                                           const float* __restrict__ nwt,
                                           const float* __restrict__ modes,
                                           float* __restrict__ pc, float* __restrict__ ps) {
    int bc = blockIdx.x;
    int b = bc / PP, chunk = bc % PP;
    int tid = threadIdx.x;
    int lane = tid & 63;
    int w = tid >> 6;
    int khalf = w & 1;
    int ig = blockIdx.y*2 + (w >> 1);
    int k = khalf*64 + lane;
    int i0 = __builtin_amdgcn_readfirstlane(ig * 16);
    float m0 = modes[k*3+0], m1 = modes[k*3+1], m2 = modes[k*3+2];
    float ac[16], as[16];
#pragma unroll
    for (int j = 0; j < 16; j++) { ac[j]=0.f; as[j]=0.f; }
    int nbase = chunk*LL;
#pragma unroll 2
    for (int t = 0; t < LL; t++) {
        int n = nbase + t;
        float nd0 = nodes[(b*NN+n)*3+0], nd1 = nodes[(b*NN+n)*3+1], nd2 = nodes[(b*NN+n)*3+2];
        float nw = nwt[b*NN+n];
        float tt = nd0*m0 + nd1*m1 + nd2*m2;
        float cv = __cosf(tt) * nw, sv = __sinf(tt) * nw;
        const float4* __restrict__ xr4 = (const float4*)&xT[((size_t)b*NN+n)*CC + i0];
        float xv[16];
        *(float4*)&xv[0]  = xr4[0];
        *(float4*)&xv[4]  = xr4[1];
        *(float4*)&xv[8]  = xr4[2];
        *(float4*)&xv[12] = xr4[3];
#pragma unroll
        for (int j = 0; j < 16; j++) {
            ac[j] = fmaf(xv[j], cv, ac[j]);
            as[j] = fmaf(xv[j], sv, as[j]);
        }
    }
    int base = (b*PP + chunk)*CC;
#pragma unroll
    for (int j = 0; j < 16; j++) {
        pc[(size_t)(base + i0 + j)*KK + k] = ac[j];
        ps[(size_t)(base + i0 + j)*KK + k] = as[j];
    }
}

__global__ void k_ared(const float* __restrict__ pc, const float* __restrict__ ps,
                       float* __restrict__ Ac, float* __restrict__ As) {
    int idx = blockIdx.x*256 + threadIdx.x;
    if (idx >= BB*CC*KK) return;
    int b = idx / (CC*KK);
    int r = idx % (CC*KK);
    float sc = 0.f, ss = 0.f;
    for (int ch = 0; ch < PP; ch++) {
        size_t o = ((size_t)(b*PP + ch)*CC)*KK + r;
        sc += pc[o]; ss += ps[o];
    }
    Ac[idx] = sc; As[idx] = ss;
}

// ---- channel mix -> 2*f_c, 2*f_s in [b][k][o] layout, + f0 ----
__global__ void __launch_bounds__(512) k_b(const float* __restrict__ Ac, const float* __restrict__ As_,
                                           const float* __restrict__ wc, const float* __restrict__ wsw,
                                           const float* __restrict__ w0, const float* __restrict__ x0,
                                           float* __restrict__ fTc, float* __restrict__ fTs,
                                           float* __restrict__ f0) {
    int b = blockIdx.x / CC, o = blockIdx.x % CC;
    int tid = threadIdx.x;
    int k = tid & 127, ig = tid >> 7;
    float fc = 0.f, fs = 0.f;
    for (int ii = 0; ii < 16; ii++) {
        int i = ig*16 + ii;
        float a_c = Ac[(b*CC+i)*KK + k];
        float a_s = As_[(b*CC+i)*KK + k];
        float wcc = wc[((size_t)(i*CC+o))*KK + k];
        float wss = wsw[((size_t)(i*CC+o))*KK + k];
        fc += a_c*wcc + a_s*wss;
        fs += a_c*wss - a_s*wcc;
    }
    __shared__ float rc[512], rs[512];
    __shared__ float f0s[64];
    rc[tid] = fc; rs[tid] = fs;
    if (tid < 64) f0s[tid] = x0[b*CC + tid] * w0[tid*CC + o];
    __syncthreads();
    if (ig == 0) {
        fc = rc[k] + rc[128+k] + rc[256+k] + rc[384+k];
        fs = rs[k] + rs[128+k] + rs[256+k] + rs[384+k];
        fTc[(b*KK+k)*CC + o] = 2.f*fc;
        fTs[(b*KK+k)*CC + o] = 2.f*fs;
    }
    if (tid == 0) {
        float acc = 0.f;
        for (int i = 0; i < 64; i++) acc += f0s[i];
        f0[b*CC+o] = acc;
    }
}

// ---- build A-panel [b][576][64]; rows 0..255 interleaved {2fc[k], -2fs[k]} ----
__global__ void k_apan(const float* __restrict__ fTc, const float* __restrict__ fTs,
                       const float* __restrict__ WT, const float* __restrict__ w2T,
                       const float* __restrict__ gwT, float* __restrict__ Apan) {
    int idx = blockIdx.x*256 + threadIdx.x;
    if (idx >= BB*KTOT*CC) return;
    int b = idx / (KTOT*CC);
    int r = idx % (KTOT*CC);
    int k = r >> 6, o = r & 63;
    float v;
    if (k < 256) {
        int kp = k >> 1;
        v = (k & 1) ? -fTs[(b*KK + kp)*CC + o] : fTc[(b*KK + kp)*CC + o];
    }
    else if (k < 320) v = WT[(k-256)*CC + o];
    else if (k < 384) v = w2T[(k-320)*CC + o];
    else              v = gwT[(k-384)*CC + o];
    Apan[idx] = v;
}

__global__ void __launch_bounds__(1024) k_scan(const int* __restrict__ counts,
                                               int* __restrict__ offsets, int* __restrict__ cursor) {
    __shared__ int part[1024];
    int b = blockIdx.x;
    int tid = threadIdx.x;
    int base = tid*16;
    int loc[16]; int s = 0;
    for (int j = 0; j < 16; j++) { loc[j] = counts[b*NN + base + j]; s += loc[j]; }
    part[tid] = s;
    __syncthreads();
    for (int off = 1; off < 1024; off <<= 1) {
        int v = (tid >= off) ? part[tid-off] : 0;
        __syncthreads();
        part[tid] += v;
        __syncthreads();
    }
    int excl = part[tid] - s;
    for (int j = 0; j < 16; j++) {
        offsets[b*NN+base+j] = excl;
        cursor[b*NN+base+j]  = excl;
        excl += loc[j];
    }
}

// ---- fill bins with packed {src, w0, w1, w2} entries ----
__global__ void k_fill(const int* __restrict__ edges, const float* __restrict__ egw,
                       int* __restrict__ cursor, float4* __restrict__ bin4) {
    int idx = blockIdx.x*256 + threadIdx.x;
    if (idx >= BB*EE) return;
    int b = idx / EE;
    int tgt = edges[(size_t)idx*2+0];
    int src = edges[(size_t)idx*2+1];
    const float* __restrict__ ew = &egw[(size_t)idx*3];
    float w0 = ew[0], w1 = ew[1], w2 = ew[2];
    int pos = atomicAdd(&cursor[b*NN+tgt], 1);
    bin4[(size_t)b*EE + pos] = make_float4(__int_as_float(src), w0, w1, w2);
}

// ---- per-node edge accumulate -> gradfT[b][g][n] ----
#define ECAP 1024
__global__ void __launch_bounds__(256) k_edge(const float* __restrict__ xT,
                                              const int* __restrict__ offsets,
                                              const float4* __restrict__ bin4,
                                              float* __restrict__ gradfT) {
    int blk = blockIdx.x;
    int b = blk / (NN/16);
    int n0 = (blk % (NN/16)) * 16;
    int tid = threadIdx.x;
    int lane = tid & 63;
    int w = tid >> 6;                 // 4 waves, 4 nodes each
    __shared__ float4 ebuf[ECAP];
    __shared__ float gl[16][193];
    __shared__ int soff[17];
    if (tid < 16) soff[tid] = offsets[b*NN + n0 + tid];
    if (tid == 16) soff[16] = (n0 + 16 < NN) ? offsets[b*NN + n0 + 16] : EE;
    __syncthreads();
    int base = soff[0];
    int end  = soff[16];
    const float* __restrict__ xTb = &xT[(size_t)b*NN*CC + lane];

    float a0[4], a1[4], a2[4], s0[4], s1[4], s2[4];
#pragma unroll
    for (int q = 0; q < 4; q++) { a0[q]=a1[q]=a2[q]=0.f; s0[q]=s1[q]=s2[q]=0.f; }

    for (int cs = base; cs < end; cs += ECAP) {
        int ce = min(cs + ECAP, end);
        __syncthreads();
        for (int t = cs + tid; t < ce; t += 256)
            ebuf[t - cs] = bin4[(size_t)b*EE + t];
        __syncthreads();
#pragma unroll
        for (int q = 0; q < 4; q++) {
            int nl = w*4 + q;
            int js = max(soff[nl], cs);
            int je = min(soff[nl+1], ce);
#pragma unroll 4
            for (int j = js; j < je; j++) {
                float4 e = ebuf[j - cs];
                int src = __float_as_int(e.x);
                float xs = xTb[(size_t)src*CC];
                a0[q] = fmaf(xs, e.y, a0[q]);
                a1[q] = fmaf(xs, e.z, a1[q]);
                a2[q] = fmaf(xs, e.w, a2[q]);
                s0[q] += e.y; s1[q] += e.z; s2[q] += e.w;
            }
        }
    }
    __syncthreads();
#pragma unroll
    for (int q = 0; q < 4; q++) {
        int nl = w*4 + q;
        float xtgt = xTb[(size_t)(n0 + nl)*CC];
        gl[nl][lane*3+0] = a0[q] - xtgt*s0[q];
        gl[nl][lane*3+1] = a1[q] - xtgt*s1[q];
        gl[nl][lane*3+2] = a2[q] - xtgt*s2[q];
    }
    __syncthreads();
    for (int t = tid; t < 16*192; t += 256) {
        int g = t >> 4, nl = t & 15;
        gradfT[((size_t)b*192+g)*NN + n0 + nl] = gl[nl][g];
    }
}

// ---- final fused GEMM: out = gelu(Apan^T·B + f0), K=576, tile 64o x 64n ----
// 128 threads, 8o x 4n thread tile -> 48 B LDS per 32 FMA (1.5 B/FMA vs 2.0 before).
// h computed in-block: c==4 accumulates both W·x and wx·x; c==5 stages
// softsign(geo)·xw into Bs from registers.
#define KC 64
__global__ void __launch_bounds__(128) k_gemm(const float* __restrict__ x,
                                              const float* __restrict__ nodes,
                                              const float* __restrict__ modes,
                                              const float* __restrict__ geo,
                                              const float* __restrict__ gradfT,
                                              const float* __restrict__ Apan,
                                              const float* __restrict__ f0,
                                              const float* __restrict__ wxT,
                                              const float* __restrict__ gwxT,
                                              float* __restrict__ out) {
    int blk = blockIdx.x;
    int b  = blk >> 8;
    int n0 = (blk & 255) * 64;
    int tid = threadIdx.x;          // 0..127
    int tx = tid & 15;              // n-group (4 n)
    int ty = tid >> 4;              // 0..7, o-group (8 o)
    __shared__ float As[KC*64];
    __shared__ float Bs[KC*64];
    __shared__ float Ws[64*64];     // wxT staged once
    __shared__ float ndl[192];
    __shared__ float geo3[192];

    {
        const float4* __restrict__ s4 = (const float4*)wxT;
        float4* d4 = (float4*)Ws;
#pragma unroll
        for (int s = 0; s < 8; s++) d4[tid + s*128] = s4[tid + s*128];
    }
    for (int s = tid; s < 192; s += 128) {
        ndl[s]  = nodes[((size_t)b*NN + n0)*3 + s];
        geo3[s] = geo[((size_t)b*GG + (s >> 6))*NN + n0 + (s & 63)];
    }

    float acc[8][4], xw[8][4];
#pragma unroll
    for (int oo = 0; oo < 8; oo++) {
        float fv = f0[b*CC + ty*8 + oo];
#pragma unroll
        for (int nn = 0; nn < 4; nn++) { acc[oo][nn] = fv; xw[oo][nn] = 0.f; }
    }
    const float* __restrict__ Ab = Apan + (size_t)b*KTOT*CC;

    for (int c = 0; c < KTOT/KC; c++) {
        __syncthreads();
        // A chunk: 1024 float4 over 128 threads
        {
            const float4* __restrict__ src = (const float4*)(Ab + (size_t)c*KC*64);
            float4* dst = (float4*)As;
#pragma unroll
            for (int s = 0; s < 8; s++) dst[tid + s*128] = src[tid + s*128];
        }
        // B chunk
        if (c < 4) {
#pragma unroll
            for (int s = 0; s < 16; s++) {
                int e = tid + s*128;        // 0..2047
                int pr = e >> 6, n = e & 63;
                int k = c*32 + pr;
                float t = ndl[n*3+0]*modes[k*3+0] + ndl[n*3+1]*modes[k*3+1]
                        + ndl[n*3+2]*modes[k*3+2];
                Bs[(2*pr)*64 + n]   = __cosf(t);
                Bs[(2*pr+1)*64 + n] = __sinf(t);
            }
        } else if (c == 5) {
#pragma unroll
            for (int oo = 0; oo < 8; oo++) {
                int i = ty*8 + oo;
                float g0 = gwxT[0*CC+i], g1 = gwxT[1*CC+i], g2 = gwxT[2*CC+i];
#pragma unroll
                for (int nn = 0; nn < 4; nn++) {
                    int n = tx*4 + nn;
                    float t = g0*geo3[n] + g1*geo3[64+n] + g2*geo3[128+n];
                    float ssv = t / (1.f + fabsf(t));
                    Bs[i*64 + n] = ssv * xw[oo][nn];
                }
            }
        } else {
            const float* __restrict__ src = (c == 4)
                ? &x[(size_t)b*CC*NN]
                : &gradfT[((size_t)b*192 + (c-6)*64)*NN];
#pragma unroll
            for (int s = 0; s < 32; s++) {
                int e = tid + s*128;
                int r = e >> 6, n = e & 63;
                Bs[e] = src[(size_t)r*NN + n0 + n];
            }
        }
        __syncthreads();
        if (c == 4) {
#pragma unroll 2
            for (int kk = 0; kk < KC; kk++) {
                float4 aL = *(const float4*)&As[kk*64 + ty*8];
                float4 aH = *(const float4*)&As[kk*64 + ty*8 + 4];
                float4 wL = *(const float4*)&Ws[kk*64 + ty*8];
                float4 wH = *(const float4*)&Ws[kk*64 + ty*8 + 4];
                float4 b4 = *(const float4*)&Bs[kk*64 + tx*4];
                float av[8] = {aL.x, aL.y, aL.z, aL.w, aH.x, aH.y, aH.z, aH.w};
                float wv[8] = {wL.x, wL.y, wL.z, wL.w, wH.x, wH.y, wH.z, wH.w};
                float bv[4] = {b4.x, b4.y, b4.z, b4.w};
#pragma unroll
                for (int oo = 0; oo < 8; oo++)
#pragma unroll
                    for (int nn = 0; nn < 4; nn++) {
                        acc[oo][nn] = fmaf(av[oo], bv[nn], acc[oo][nn]);
                        xw[oo][nn]  = fmaf(wv[oo], bv[nn], xw[oo][nn]);
                    }
            }
        } else {
#pragma unroll 2
            for (int kk = 0; kk < KC; kk++) {
                float4 aL = *(const float4*)&As[kk*64 + ty*8];
                float4 aH = *(const float4*)&As[kk*64 + ty*8 + 4];
                float4 b4 = *(const float4*)&Bs[kk*64 + tx*4];
                float av[8] = {aL.x, aL.y, aL.z, aL.w, aH.x, aH.y, aH.z, aH.w};
                float bv[4] = {b4.x, b4.y, b4.z, b4.w};
#pragma unroll
                for (int oo = 0; oo < 8; oo++)
#pragma unroll
                    for (int nn = 0; nn < 4; nn++)
                        acc[oo][nn] = fmaf(av[oo], bv[nn], acc[oo][nn]);
            }
        }
    }
    // epilogue: exact GELU + float4 store
#pragma unroll
    for (int oo = 0; oo < 8; oo++) {
        int o = ty*8 + oo;
        float4 r4;
        float* rp = (float*)&r4;
#pragma unroll
        for (int nn = 0; nn < 4; nn++) {
            float v = acc[oo][nn];
            rp[nn] = 0.5f * v * (1.f + erff(v * 0.70710678118654752f));
        }
        *(float4*)&out[((size_t)b*CC + o)*NN + n0 + tx*4] = r4;
    }
}

extern "C" void kernel_launch(void* const* d_in, const int* in_sizes, int n_in,
                              void* d_out, int out_size, void* d_ws, size_t ws_size,
                              hipStream_t stream) {
    const float* x      = (const float*)d_in[0];
    const float* nodes  = (const float*)d_in[1];
    const float* nwt    = (const float*)d_in[2];
    const float* geo    = (const float*)d_in[3];
    const int*   edges  = (const int*)d_in[4];
    const float* egw    = (const float*)d_in[5];
    const float* modes  = (const float*)d_in[6];
    const float* wc     = (const float*)d_in[7];
    const float* wsw    = (const float*)d_in[8];
    const float* w0     = (const float*)d_in[9];
    const float* W      = (const float*)d_in[10];
    const float* gw     = (const float*)d_in[11];
    const float* geo_wx = (const float*)d_in[12];
    const float* wx     = (const float*)d_in[13];
    const float* w2     = (const float*)d_in[14];

    float* ws   = (float*)d_ws;
    float* xT   = ws + OFF_XT;
    float* pc   = ws + OFF_PC;
    float* ps   = ws + OFF_PS;
    float* Ac   = ws + OFF_AC;
    float* As   = ws + OFF_AS;
    float* fTc  = ws + OFF_FTC;
    float* fTs  = ws + OFF_FTS;
    float* f0   = ws + OFF_F0;
    float* x0   = ws + OFF_X0;
    int*  counts = (int*)(ws + OFF_CNT);
    int*  offs   = (int*)(ws + OFF_OFFS);
    int*  cur    = (int*)(ws + OFF_CUR);
    float4* bin4 = (float4*)(ws + OFF_BIN4);
    float* gradfT = ws + OFF_GRT;
    float* Apan   = ws + OFF_APAN;
    float* WT   = ws + OFF_WT;
    float* wxT  = ws + OFF_WXT;
    float* w2T  = ws + OFF_W2T;
    float* gwT  = ws + OFF_GWT;
    float* gwxT = ws + OFF_GWXT;
    float* out  = (float*)d_out;

    hipMemsetAsync(counts, 0, (size_t)(BB*NN)*sizeof(int), stream);

    k_prep <<<48, 256, 0, stream>>>(W, gw, geo_wx, wx, w2, WT, wxT, w2T, gwT, gwxT);
    k_pre  <<<BB*(NN/64) + BB*CC + (BB*EE)/256, 256, 0, stream>>>(x, nwt, edges, xT, x0, counts);
    k_a    <<<dim3(BB*PP, 2), 256, 0, stream>>>(xT, nodes, nwt, modes, pc, ps);
    k_ared <<<(BB*CC*KK)/256, 256, 0, stream>>>(pc, ps, Ac, As);
    k_b    <<<BB*CC, 512, 0, stream>>>(Ac, As, wc, wsw, w0, x0, fTc, fTs, f0);
    k_apan <<<(BB*KTOT*CC + 255)/256, 256, 0, stream>>>(fTc, fTs, WT, w2T, gwT, Apan);
    k_scan <<<BB, 1024, 0, stream>>>(counts, offs, cur);
    k_fill <<<(BB*EE)/256, 256, 0, stream>>>(edges, egw, cur, bin4);
    k_edge <<<BB*(NN/16), 256, 0, stream>>>(xT, offs, bin4, gradfT);
    k_gemm <<<BB*(NN/64), 128, 0, stream>>>(x, nodes, modes, geo, gradfT, Apan, f0,
                                            wxT, gwxT, out);
}

// Round 10
// 276.949 us; speedup vs baseline: 1.1988x; 1.1988x over previous
//
#include <hip/hip_runtime.h>
#include <hip/hip_fp16.h>
#include <math.h>

#define BB 2
#define CC 64
#define NN 16384
#define DD 3
#define KK 128
#define EE 262144
#define GG 3
#define PP 128           // n-chunks for spectral-forward partials
#define LL (NN/PP)       // 128 n per chunk
#define KTOT 576         // concat K: 256 interleaved cos/sin + 64 x + 64 h + 192 gradf

// ---- workspace layout (float elements) ----
constexpr size_t OFF_XT   = 0;                                  // xT[b][n][i]
constexpr size_t OFF_PC   = OFF_XT   + (size_t)BB*NN*CC;        // partial A_c
constexpr size_t OFF_PS   = OFF_PC   + (size_t)BB*PP*CC*KK;     // partial A_s
constexpr size_t OFF_BIN4 = OFF_PC;                             // float4 binlist[b][E] (aliases pc/ps)
constexpr size_t OFF_AC   = OFF_PS   + (size_t)BB*PP*CC*KK;     // A_c[b][i][k]
constexpr size_t OFF_AS   = OFF_AC   + (size_t)BB*CC*KK;
constexpr size_t OFF_F0   = OFF_AS   + (size_t)BB*CC*KK;        // f0[b][o]
constexpr size_t OFF_X0   = OFF_F0   + (size_t)BB*CC;           // x0[b][i]
constexpr size_t OFF_CNT  = OFF_X0   + (size_t)BB*CC;           // int counts (zeroed)
constexpr size_t OFF_OFFS = OFF_CNT  + (size_t)BB*NN;           // int offsets
constexpr size_t OFF_RANK = OFF_OFFS + (size_t)BB*NN;           // int rank[b][E]
constexpr size_t OFF_GRT  = OFF_RANK + (size_t)BB*EE;           // gradfT[b][g][n]
constexpr size_t OFF_APAN = OFF_GRT  + (size_t)BB*192*NN;       // Apan[b][576][64]
constexpr size_t OFF_WXT  = OFF_APAN + (size_t)BB*KTOT*CC;      // wx^T [j][i]
constexpr size_t OFF_GWXT = OFF_WXT  + (size_t)CC*CC;           // geo_wx^T [g][i]

// ---- small transposes + static A-panel rows (W/w2/gw for both batches) ----
__global__ void k_prep(const float* __restrict__ W, const float* __restrict__ gw,
                       const float* __restrict__ geo_wx, const float* __restrict__ wx,
                       const float* __restrict__ w2,
                       float* wxT, float* gwxT, float* Apan) {
    int idx = blockIdx.x*256 + threadIdx.x;
    if (idx < CC*CC) {
        int j = idx>>6, o = idx&63;
        float wv  = W[o*CC+j];
        float w2v = w2[o*CC+j];      // here j plays the role of i
        Apan[((size_t)0*KTOT + 256 + j)*CC + o] = wv;
        Apan[((size_t)1*KTOT + 256 + j)*CC + o] = wv;
        Apan[((size_t)0*KTOT + 320 + j)*CC + o] = w2v;
        Apan[((size_t)1*KTOT + 320 + j)*CC + o] = w2v;
        wxT[idx] = wx[(idx&63)*CC + (idx>>6)];   // wxT[j][i] = wx[i][j]
    }
    if (idx < CC*CC*DD) {
        int g = idx>>6, o = idx&63;
        float gv = gw[o*(CC*DD)+g];
        Apan[((size_t)0*KTOT + 384 + g)*CC + o] = gv;
        Apan[((size_t)1*KTOT + 384 + g)*CC + o] = gv;
    }
    if (idx < GG*CC) { int g = idx>>6, i = idx&63; gwxT[idx] = geo_wx[i*GG+g]; }
}

// ---- fused pre-pass: transpose x -> xT, x0 reduction, edge-count+rank ----
__global__ void __launch_bounds__(256) k_pre(const float* __restrict__ x,
                                             const float* __restrict__ nwt,
                                             const int* __restrict__ edges,
                                             float* __restrict__ xT,
                                             float* __restrict__ x0,
                                             int* __restrict__ counts,
                                             int* __restrict__ rank) {
    int blk = blockIdx.x;
    int tid = threadIdx.x;
    __shared__ float tile[64][65];
    __shared__ float red[256];
    if (blk < BB*(NN/64)) {
        int b = blk / (NN/64);
        int n0 = (blk % (NN/64)) * 64;
        int c = tid & 63, r4 = tid >> 6;
        for (int rr = 0; rr < 16; rr++) {
            int i = r4*16 + rr;
            tile[i][c] = x[((size_t)b*CC + i)*NN + n0 + c];
        }
        __syncthreads();
        for (int rr = 0; rr < 16; rr++) {
            int nn = r4*16 + rr;
            xT[((size_t)b*NN + n0 + nn)*CC + c] = tile[c][nn];
        }
    } else if (blk < BB*(NN/64) + BB*CC) {
        int bi = blk - BB*(NN/64);
        int b = bi >> 6, i = bi & 63;
        const float4* __restrict__ xr = (const float4*)&x[((size_t)b*CC + i)*NN];
        const float4* __restrict__ wr = (const float4*)&nwt[(size_t)b*NN];
        float s = 0.f;
        for (int t = tid; t < NN/4; t += 256) {
            float4 xv = xr[t];
            float4 wv = wr[t];
            s += xv.x*wv.x + xv.y*wv.y + xv.z*wv.z + xv.w*wv.w;
        }
        red[tid] = s;
        __syncthreads();
        for (int off = 128; off > 0; off >>= 1) {
            if (tid < off) red[tid] += red[tid+off];
            __syncthreads();
        }
        if (tid == 0) x0[b*CC + i] = red[0];
    } else {
        int idx = (blk - (BB*(NN/64) + BB*CC))*256 + tid;
        if (idx < BB*EE) {
            int tgt = edges[(size_t)idx*2 + 0];
            int b = idx / EE;
            rank[idx] = atomicAdd(&counts[b*NN + tgt], 1);
        }
    }
}

// ---- spectral forward partials: A_c/A_s[b][i][k] over n-chunks ----
__global__ void __launch_bounds__(256) k_a(const float* __restrict__ xT,
                                           const float* __restrict__ nodes,
                                           const float* __restrict__ nwt,
                                           const float* __restrict__ modes,
                                           float* __restrict__ pc, float* __restrict__ ps) {
    int bc = blockIdx.x;
    int b = bc / PP, chunk = bc % PP;
    int tid = threadIdx.x;
    int lane = tid & 63;
    int w = tid >> 6;
    int khalf = w & 1;
    int ig = blockIdx.y*2 + (w >> 1);
    int k = khalf*64 + lane;
    int i0 = __builtin_amdgcn_readfirstlane(ig * 16);
    float m0 = modes[k*3+0], m1 = modes[k*3+1], m2 = modes[k*3+2];
    float ac[16], as[16];
#pragma unroll
    for (int j = 0; j < 16; j++) { ac[j]=0.f; as[j]=0.f; }
    int nbase = chunk*LL;
#pragma unroll 2
    for (int t = 0; t < LL; t++) {
        int n = nbase + t;
        float nd0 = nodes[(b*NN+n)*3+0], nd1 = nodes[(b*NN+n)*3+1], nd2 = nodes[(b*NN+n)*3+2];
        float nw = nwt[b*NN+n];
        float tt = nd0*m0 + nd1*m1 + nd2*m2;
        float cv = __cosf(tt) * nw, sv = __sinf(tt) * nw;
        const float4* __restrict__ xr4 = (const float4*)&xT[((size_t)b*NN+n)*CC + i0];
        float xv[16];
        *(float4*)&xv[0]  = xr4[0];
        *(float4*)&xv[4]  = xr4[1];
        *(float4*)&xv[8]  = xr4[2];
        *(float4*)&xv[12] = xr4[3];
#pragma unroll
        for (int j = 0; j < 16; j++) {
            ac[j] = fmaf(xv[j], cv, ac[j]);
            as[j] = fmaf(xv[j], sv, as[j]);
        }
    }
    int base = (b*PP + chunk)*CC;
#pragma unroll
    for (int j = 0; j < 16; j++) {
        pc[(size_t)(base + i0 + j)*KK + k] = ac[j];
        ps[(size_t)(base + i0 + j)*KK + k] = as[j];
    }
}

__global__ void k_ared(const float* __restrict__ pc, const float* __restrict__ ps,
                       float* __restrict__ Ac, float* __restrict__ As) {
    int idx = blockIdx.x*256 + threadIdx.x;
    if (idx >= BB*CC*KK) return;
    int b = idx / (CC*KK);
    int r = idx % (CC*KK);
    float sc = 0.f, ss = 0.f;
    for (int ch = 0; ch < PP; ch++) {
        size_t o = ((size_t)(b*PP + ch)*CC)*KK + r;
        sc += pc[o]; ss += ps[o];
    }
    Ac[idx] = sc; As[idx] = ss;
}

// ---- channel mix -> interleaved A-panel rows {2fc[k], -2fs[k]}, + f0 ----
// grid: (b, o, khalf) = BB*CC*2 blocks x 256 threads (k_local = tid&63, ig = tid>>6)
__global__ void __launch_bounds__(256) k_b(const float* __restrict__ Ac, const float* __restrict__ As_,
                                           const float* __restrict__ wc, const float* __restrict__ wsw,
                                           const float* __restrict__ w0, const float* __restrict__ x0,
                                           float* __restrict__ Apan, float* __restrict__ f0) {
    int idx = blockIdx.x;
    int b = idx / (CC*2);
    int rem = idx % (CC*2);
    int o = rem >> 1, khalf = rem & 1;
    int tid = threadIdx.x;
    int kl = tid & 63, ig = tid >> 6;
    int k = khalf*64 + kl;
    float fc = 0.f, fs = 0.f;
    for (int ii = 0; ii < 16; ii++) {
        int i = ig*16 + ii;
        float a_c = Ac[(b*CC+i)*KK + k];
        float a_s = As_[(b*CC+i)*KK + k];
        float wcc = wc[((size_t)(i*CC+o))*KK + k];
        float wss = wsw[((size_t)(i*CC+o))*KK + k];
        fc += a_c*wcc + a_s*wss;
        fs += a_c*wss - a_s*wcc;
    }
    __shared__ float rc[256], rs[256];
    __shared__ float f0s[64];
    rc[tid] = fc; rs[tid] = fs;
    if (khalf == 0 && tid < 64) f0s[tid] = x0[b*CC + tid] * w0[tid*CC + o];
    __syncthreads();
    if (ig == 0) {
        fc = rc[kl] + rc[64+kl] + rc[128+kl] + rc[192+kl];
        fs = rs[kl] + rs[64+kl] + rs[128+kl] + rs[192+kl];
        Apan[((size_t)b*KTOT + 2*k)*CC + o]     = 2.f*fc;
        Apan[((size_t)b*KTOT + 2*k + 1)*CC + o] = -2.f*fs;
    }
    if (khalf == 0 && tid == 0) {
        float acc = 0.f;
        for (int i = 0; i < 64; i++) acc += f0s[i];
        f0[b*CC+o] = acc;
    }
}

__global__ void __launch_bounds__(1024) k_scan(const int* __restrict__ counts,
                                               int* __restrict__ offsets) {
    __shared__ int part[1024];
    int b = blockIdx.x;
    int tid = threadIdx.x;
    int base = tid*16;
    int loc[16]; int s = 0;
    for (int j = 0; j < 16; j++) { loc[j] = counts[b*NN + base + j]; s += loc[j]; }
    part[tid] = s;
    __syncthreads();
    for (int off = 1; off < 1024; off <<= 1) {
        int v = (tid >= off) ? part[tid-off] : 0;
        __syncthreads();
        part[tid] += v;
        __syncthreads();
    }
    int excl = part[tid] - s;
    for (int j = 0; j < 16; j++) {
        offsets[b*NN+base+j] = excl;
        excl += loc[j];
    }
}

// ---- fill bins (atomic-free: rank precomputed in k_pre) ----
__global__ void k_fill(const int* __restrict__ edges, const float* __restrict__ egw,
                       const int* __restrict__ offs, const int* __restrict__ rank,
                       float4* __restrict__ bin4) {
    int idx = blockIdx.x*256 + threadIdx.x;
    if (idx >= BB*EE) return;
    int b = idx / EE;
    int tgt = edges[(size_t)idx*2+0];
    int src = edges[(size_t)idx*2+1];
    const float* __restrict__ ew = &egw[(size_t)idx*3];
    float w0 = ew[0], w1 = ew[1], w2 = ew[2];
    int pos = offs[b*NN+tgt] + rank[idx];
    bin4[(size_t)b*EE + pos] = make_float4(__int_as_float(src), w0, w1, w2);
}

// ---- per-node edge accumulate -> gradfT[b][g][n] ----
#define ECAP 1024
__global__ void __launch_bounds__(256) k_edge(const float* __restrict__ xT,
                                              const int* __restrict__ offsets,
                                              const float4* __restrict__ bin4,
                                              float* __restrict__ gradfT) {
    int blk = blockIdx.x;
    int b = blk / (NN/16);
    int n0 = (blk % (NN/16)) * 16;
    int tid = threadIdx.x;
    int lane = tid & 63;
    int w = tid >> 6;                 // 4 waves, 4 nodes each
    __shared__ float4 ebuf[ECAP];
    __shared__ float gl[16][193];
    __shared__ int soff[17];
    if (tid < 16) soff[tid] = offsets[b*NN + n0 + tid];
    if (tid == 16) soff[16] = (n0 + 16 < NN) ? offsets[b*NN + n0 + 16] : EE;
    __syncthreads();
    int base = soff[0];
    int end  = soff[16];
    const float* __restrict__ xTb = &xT[(size_t)b*NN*CC + lane];

    float a0[4], a1[4], a2[4], s0[4], s1[4], s2[4];
#pragma unroll
    for (int q = 0; q < 4; q++) { a0[q]=a1[q]=a2[q]=0.f; s0[q]=s1[q]=s2[q]=0.f; }

    for (int cs = base; cs < end; cs += ECAP) {
        int ce = min(cs + ECAP, end);
        __syncthreads();
        for (int t = cs + tid; t < ce; t += 256)
            ebuf[t - cs] = bin4[(size_t)b*EE + t];
        __syncthreads();
#pragma unroll
        for (int q = 0; q < 4; q++) {
            int nl = w*4 + q;
            int js = max(soff[nl], cs);
            int je = min(soff[nl+1], ce);
#pragma unroll 4
            for (int j = js; j < je; j++) {
                float4 e = ebuf[j - cs];
                int src = __float_as_int(e.x);
                float xs = xTb[(size_t)src*CC];
                a0[q] = fmaf(xs, e.y, a0[q]);
                a1[q] = fmaf(xs, e.z, a1[q]);
                a2[q] = fmaf(xs, e.w, a2[q]);
                s0[q] += e.y; s1[q] += e.z; s2[q] += e.w;
            }
        }
    }
    __syncthreads();
#pragma unroll
    for (int q = 0; q < 4; q++) {
        int nl = w*4 + q;
        float xtgt = xTb[(size_t)(n0 + nl)*CC];
        gl[nl][lane*3+0] = a0[q] - xtgt*s0[q];
        gl[nl][lane*3+1] = a1[q] - xtgt*s1[q];
        gl[nl][lane*3+2] = a2[q] - xtgt*s2[q];
    }
    __syncthreads();
    for (int t = tid; t < 16*192; t += 256) {
        int g = t >> 4, nl = t & 15;
        gradfT[((size_t)b*192+g)*NN + n0 + nl] = gl[nl][g];
    }
}

// ---- final fused GEMM: out = gelu(Apan^T·B + f0), K=576, tile 64o x 64n ----
// 256 threads, 4x4 thread tile (r8 configuration — 8 waves/CU).
// h computed in-block: c==4 accumulates both W·x and wx·x; c==5 stages
// softsign(geo)·xw into Bs from registers.
#define KC 64
__global__ void __launch_bounds__(256) k_gemm(const float* __restrict__ x,
                                              const float* __restrict__ nodes,
                                              const float* __restrict__ modes,
                                              const float* __restrict__ geo,
                                              const float* __restrict__ gradfT,
                                              const float* __restrict__ Apan,
                                              const float* __restrict__ f0,
                                              const float* __restrict__ wxT,
                                              const float* __restrict__ gwxT,
                                              float* __restrict__ out) {
    int blk = blockIdx.x;
    int b  = blk >> 8;
    int n0 = (blk & 255) * 64;
    int tid = threadIdx.x;
    int tx = tid & 15;                 // n / 4
    int ty = tid >> 4;                 // o / 4
    __shared__ float As[KC*64];
    __shared__ float Bs[KC*64];
    __shared__ float Ws[64*64];        // wxT staged once
    __shared__ float ndl[192];
    __shared__ float geo3[192];

    {
        const float4* __restrict__ s4 = (const float4*)wxT;
        float4* d4 = (float4*)Ws;
        for (int s = tid; s < 1024; s += 256) d4[s] = s4[s];
    }
    if (tid < 192) ndl[tid]  = nodes[((size_t)b*NN + n0)*3 + tid];
    if (tid < 192) geo3[tid] = geo[((size_t)b*GG + (tid >> 6))*NN + n0 + (tid & 63)];

    float acc[4][4], xw[4][4];
#pragma unroll
    for (int oo = 0; oo < 4; oo++) {
        float fv = f0[b*CC + ty*4 + oo];
#pragma unroll
        for (int nn = 0; nn < 4; nn++) { acc[oo][nn] = fv; xw[oo][nn] = 0.f; }
    }
    const float* __restrict__ Ab = Apan + (size_t)b*KTOT*CC;

    for (int c = 0; c < KTOT/KC; c++) {
        __syncthreads();
        // A chunk: linear float4 copy
        {
            const float4* __restrict__ src = (const float4*)(Ab + (size_t)c*KC*64);
            float4* dst = (float4*)As;
#pragma unroll
            for (int s = 0; s < 4; s++) dst[tid + s*256] = src[tid + s*256];
        }
        // B chunk
        if (c < 4) {
            // 32 interleaved {cos,sin} pairs; one trig eval per (k,n)
#pragma unroll
            for (int s = 0; s < 8; s++) {
                int e = tid + s*256;        // 0..2047
                int pr = e >> 6, n = e & 63;
                int k = c*32 + pr;
                float t = ndl[n*3+0]*modes[k*3+0] + ndl[n*3+1]*modes[k*3+1]
                        + ndl[n*3+2]*modes[k*3+2];
                Bs[(2*pr)*64 + n]   = __cosf(t);
                Bs[(2*pr+1)*64 + n] = __sinf(t);
            }
        } else if (c == 5) {
            // h tile from xw registers (xw finalized in c==4 compute)
#pragma unroll
            for (int oo = 0; oo < 4; oo++) {
                int i = ty*4 + oo;
                float g0 = gwxT[0*CC+i], g1 = gwxT[1*CC+i], g2 = gwxT[2*CC+i];
#pragma unroll
                for (int nn = 0; nn < 4; nn++) {
                    int n = tx*4 + nn;
                    float t = g0*geo3[n] + g1*geo3[64+n] + g2*geo3[128+n];
                    float ssv = t / (1.f + fabsf(t));
                    Bs[i*64 + n] = ssv * xw[oo][nn];
                }
            }
        } else {
            const float* __restrict__ src = (c == 4)
                ? &x[(size_t)b*CC*NN]
                : &gradfT[((size_t)b*192 + (c-6)*64)*NN];
#pragma unroll
            for (int s = 0; s < 16; s++) {
                int e = tid + s*256;
                int r = e >> 6, n = e & 63;
                Bs[e] = src[(size_t)r*NN + n0 + n];
            }
        }
        __syncthreads();
        if (c == 4) {
#pragma unroll 2
            for (int kk = 0; kk < KC; kk++) {
                float4 a4 = *(const float4*)&As[kk*64 + ty*4];
                float4 w4 = *(const float4*)&Ws[kk*64 + ty*4];
                float4 b4 = *(const float4*)&Bs[kk*64 + tx*4];
                float av[4] = {a4.x, a4.y, a4.z, a4.w};
                float wv[4] = {w4.x, w4.y, w4.z, w4.w};
                float bv[4] = {b4.x, b4.y, b4.z, b4.w};
#pragma unroll
                for (int oo = 0; oo < 4; oo++)
#pragma unroll
                    for (int nn = 0; nn < 4; nn++) {
                        acc[oo][nn] = fmaf(av[oo], bv[nn], acc[oo][nn]);
                        xw[oo][nn]  = fmaf(wv[oo], bv[nn], xw[oo][nn]);
                    }
            }
        } else {
#pragma unroll 4
            for (int kk = 0; kk < KC; kk++) {
                float4 a4 = *(const float4*)&As[kk*64 + ty*4];
                float4 b4 = *(const float4*)&Bs[kk*64 + tx*4];
                float av[4] = {a4.x, a4.y, a4.z, a4.w};
                float bv[4] = {b4.x, b4.y, b4.z, b4.w};
#pragma unroll
                for (int oo = 0; oo < 4; oo++)
#pragma unroll
                    for (int nn = 0; nn < 4; nn++)
                        acc[oo][nn] = fmaf(av[oo], bv[nn], acc[oo][nn]);
            }
        }
    }
    // epilogue: exact GELU + float4 store
#pragma unroll
    for (int oo = 0; oo < 4; oo++) {
        int o = ty*4 + oo;
        float4 r4;
        float* rp = (float*)&r4;
#pragma unroll
        for (int nn = 0; nn < 4; nn++) {
            float v = acc[oo][nn];
            rp[nn] = 0.5f * v * (1.f + erff(v * 0.70710678118654752f));
        }
        *(float4*)&out[((size_t)b*CC + o)*NN + n0 + tx*4] = r4;
    }
}

extern "C" void kernel_launch(void* const* d_in, const int* in_sizes, int n_in,
                              void* d_out, int out_size, void* d_ws, size_t ws_size,
                              hipStream_t stream) {
    const float* x      = (const float*)d_in[0];
    const float* nodes  = (const float*)d_in[1];
    const float* nwt    = (const float*)d_in[2];
    const float* geo    = (const float*)d_in[3];
    const int*   edges  = (const int*)d_in[4];
    const float* egw    = (const float*)d_in[5];
    const float* modes  = (const float*)d_in[6];
    const float* wc     = (const float*)d_in[7];
    const float* wsw    = (const float*)d_in[8];
    const float* w0     = (const float*)d_in[9];
    const float* W      = (const float*)d_in[10];
    const float* gw     = (const float*)d_in[11];
    const float* geo_wx = (const float*)d_in[12];
    const float* wx     = (const float*)d_in[13];
    const float* w2     = (const float*)d_in[14];

    float* ws   = (float*)d_ws;
    float* xT   = ws + OFF_XT;
    float* pc   = ws + OFF_PC;
    float* ps   = ws + OFF_PS;
    float* Ac   = ws + OFF_AC;
    float* As   = ws + OFF_AS;
    float* f0   = ws + OFF_F0;
    float* x0   = ws + OFF_X0;
    int*  counts = (int*)(ws + OFF_CNT);
    int*  offs   = (int*)(ws + OFF_OFFS);
    int*  rank   = (int*)(ws + OFF_RANK);
    float4* bin4 = (float4*)(ws + OFF_BIN4);
    float* gradfT = ws + OFF_GRT;
    float* Apan   = ws + OFF_APAN;
    float* wxT  = ws + OFF_WXT;
    float* gwxT = ws + OFF_GWXT;
    float* out  = (float*)d_out;

    hipMemsetAsync(counts, 0, (size_t)(BB*NN)*sizeof(int), stream);

    k_prep <<<48, 256, 0, stream>>>(W, gw, geo_wx, wx, w2, wxT, gwxT, Apan);
    k_pre  <<<BB*(NN/64) + BB*CC + (BB*EE)/256, 256, 0, stream>>>(x, nwt, edges, xT, x0,
                                                                  counts, rank);
    k_a    <<<dim3(BB*PP, 2), 256, 0, stream>>>(xT, nodes, nwt, modes, pc, ps);
    k_ared <<<(BB*CC*KK)/256, 256, 0, stream>>>(pc, ps, Ac, As);
    k_b    <<<BB*CC*2, 256, 0, stream>>>(Ac, As, wc, wsw, w0, x0, Apan, f0);
    k_scan <<<BB, 1024, 0, stream>>>(counts, offs);
    k_fill <<<(BB*EE)/256, 256, 0, stream>>>(edges, egw, offs, rank, bin4);
    k_edge <<<BB*(NN/16), 256, 0, stream>>>(xT, offs, bin4, gradfT);
    k_gemm <<<BB*(NN/64), 256, 0, stream>>>(x, nodes, modes, geo, gradfT, Apan, f0,
                                            wxT, gwxT, out);
}

// Round 11
// 256.962 us; speedup vs baseline: 1.2920x; 1.0778x over previous
//
#include <hip/hip_runtime.h>
#include <hip/hip_fp16.h>
#include <math.h>

#define BB 2
#define CC 64
#define NN 16384
#define DD 3
#define KK 128
#define EE 262144
#define GG 3
#define PP 128           // n-chunks for spectral-forward partials
#define LL (NN/PP)       // 128 n per chunk
#define KTOT 576         // concat K: 256 interleaved cos/sin + 64 x + 64 h + 192 gradf

typedef short bf16x8 __attribute__((ext_vector_type(8)));
typedef float f32x4  __attribute__((ext_vector_type(4)));

__device__ __forceinline__ short f2bf(float f) {
    unsigned u = __float_as_uint(f);
    u += 0x7FFF + ((u >> 16) & 1);          // round-to-nearest-even
    return (short)(u >> 16);
}

// ---- workspace layout (float elements) ----
constexpr size_t OFF_XT   = 0;                                  // xT[b][n][i]
constexpr size_t OFF_PC   = OFF_XT   + (size_t)BB*NN*CC;        // partial A_c
constexpr size_t OFF_PS   = OFF_PC   + (size_t)BB*PP*CC*KK;     // partial A_s
constexpr size_t OFF_BIN4 = OFF_PC;                             // float4 binlist[b][E] (aliases pc/ps)
constexpr size_t OFF_AC   = OFF_PS   + (size_t)BB*PP*CC*KK;     // A_c[b][i][k]
constexpr size_t OFF_AS   = OFF_AC   + (size_t)BB*CC*KK;
constexpr size_t OFF_F0   = OFF_AS   + (size_t)BB*CC*KK;        // f0[b][o]
constexpr size_t OFF_X0   = OFF_F0   + (size_t)BB*CC;           // x0[b][i]
constexpr size_t OFF_CNT  = OFF_X0   + (size_t)BB*CC;           // int counts (zeroed)
constexpr size_t OFF_OFFS = OFF_CNT  + (size_t)BB*NN;           // int offsets
constexpr size_t OFF_RANK = OFF_OFFS + (size_t)BB*NN;           // int rank[b][E]
constexpr size_t OFF_GRT  = OFF_RANK + (size_t)BB*EE;           // gradfT[b][g][n]
constexpr size_t OFF_APAN = OFF_GRT  + (size_t)BB*192*NN;       // bf16 ApanT[b][64 o][576 k]
constexpr size_t OFF_GWXT = OFF_APAN + (size_t)BB*KTOT*CC;      // geo_wx^T [g][i] (fp32)

// ---- small transposes + static A-panel rows (bf16, [o][k]) ----
__global__ void k_prep(const float* __restrict__ W, const float* __restrict__ gw,
                       const float* __restrict__ geo_wx, const float* __restrict__ w2,
                       float* gwxT, short* ApanB) {
    int idx = blockIdx.x*256 + threadIdx.x;
    if (idx < CC*CC) {
        int j = idx>>6, o = idx&63;
        short wv  = f2bf(W[o*CC+j]);
        short w2v = f2bf(w2[o*CC+j]);
        ApanB[((size_t)(0*CC+o))*KTOT + 256 + j] = wv;
        ApanB[((size_t)(1*CC+o))*KTOT + 256 + j] = wv;
        ApanB[((size_t)(0*CC+o))*KTOT + 320 + j] = w2v;
        ApanB[((size_t)(1*CC+o))*KTOT + 320 + j] = w2v;
    }
    if (idx < CC*CC*DD) {
        int g = idx>>6, o = idx&63;
        short gv = f2bf(gw[o*(CC*DD)+g]);
        ApanB[((size_t)(0*CC+o))*KTOT + 384 + g] = gv;
        ApanB[((size_t)(1*CC+o))*KTOT + 384 + g] = gv;
    }
    if (idx < GG*CC) { int g = idx>>6, i = idx&63; gwxT[idx] = geo_wx[i*GG+g]; }
}

// ---- fused pre-pass: transpose x -> xT, x0 reduction, edge-count+rank ----
__global__ void __launch_bounds__(256) k_pre(const float* __restrict__ x,
                                             const float* __restrict__ nwt,
                                             const int* __restrict__ edges,
                                             float* __restrict__ xT,
                                             float* __restrict__ x0,
                                             int* __restrict__ counts,
                                             int* __restrict__ rank) {
    int blk = blockIdx.x;
    int tid = threadIdx.x;
    __shared__ float tile[64][65];
    __shared__ float red[256];
    if (blk < BB*(NN/64)) {
        int b = blk / (NN/64);
        int n0 = (blk % (NN/64)) * 64;
        int c = tid & 63, r4 = tid >> 6;
        for (int rr = 0; rr < 16; rr++) {
            int i = r4*16 + rr;
            tile[i][c] = x[((size_t)b*CC + i)*NN + n0 + c];
        }
        __syncthreads();
        for (int rr = 0; rr < 16; rr++) {
            int nn = r4*16 + rr;
            xT[((size_t)b*NN + n0 + nn)*CC + c] = tile[c][nn];
        }
    } else if (blk < BB*(NN/64) + BB*CC) {
        int bi = blk - BB*(NN/64);
        int b = bi >> 6, i = bi & 63;
        const float4* __restrict__ xr = (const float4*)&x[((size_t)b*CC + i)*NN];
        const float4* __restrict__ wr = (const float4*)&nwt[(size_t)b*NN];
        float s = 0.f;
        for (int t = tid; t < NN/4; t += 256) {
            float4 xv = xr[t];
            float4 wv = wr[t];
            s += xv.x*wv.x + xv.y*wv.y + xv.z*wv.z + xv.w*wv.w;
        }
        red[tid] = s;
        __syncthreads();
        for (int off = 128; off > 0; off >>= 1) {
            if (tid < off) red[tid] += red[tid+off];
            __syncthreads();
        }
        if (tid == 0) x0[b*CC + i] = red[0];
    } else {
        int idx = (blk - (BB*(NN/64) + BB*CC))*256 + tid;
        if (idx < BB*EE) {
            int tgt = edges[(size_t)idx*2 + 0];
            int b = idx / EE;
            rank[idx] = atomicAdd(&counts[b*NN + tgt], 1);
        }
    }
}

// ---- spectral forward partials: A_c/A_s[b][i][k] over n-chunks ----
__global__ void __launch_bounds__(256) k_a(const float* __restrict__ xT,
                                           const float* __restrict__ nodes,
                                           const float* __restrict__ nwt,
                                           const float* __restrict__ modes,
                                           float* __restrict__ pc, float* __restrict__ ps) {
    int bc = blockIdx.x;
    int b = bc / PP, chunk = bc % PP;
    int tid = threadIdx.x;
    int lane = tid & 63;
    int w = tid >> 6;
    int khalf = w & 1;
    int ig = blockIdx.y*2 + (w >> 1);
    int k = khalf*64 + lane;
    int i0 = __builtin_amdgcn_readfirstlane(ig * 16);
    float m0 = modes[k*3+0], m1 = modes[k*3+1], m2 = modes[k*3+2];
    float ac[16], as[16];
#pragma unroll
    for (int j = 0; j < 16; j++) { ac[j]=0.f; as[j]=0.f; }
    int nbase = chunk*LL;
#pragma unroll 2
    for (int t = 0; t < LL; t++) {
        int n = nbase + t;
        float nd0 = nodes[(b*NN+n)*3+0], nd1 = nodes[(b*NN+n)*3+1], nd2 = nodes[(b*NN+n)*3+2];
        float nw = nwt[b*NN+n];
        float tt = nd0*m0 + nd1*m1 + nd2*m2;
        float cv = __cosf(tt) * nw, sv = __sinf(tt) * nw;
        const float4* __restrict__ xr4 = (const float4*)&xT[((size_t)b*NN+n)*CC + i0];
        float xv[16];
        *(float4*)&xv[0]  = xr4[0];
        *(float4*)&xv[4]  = xr4[1];
        *(float4*)&xv[8]  = xr4[2];
        *(float4*)&xv[12] = xr4[3];
#pragma unroll
        for (int j = 0; j < 16; j++) {
            ac[j] = fmaf(xv[j], cv, ac[j]);
            as[j] = fmaf(xv[j], sv, as[j]);
        }
    }
    int base = (b*PP + chunk)*CC;
#pragma unroll
    for (int j = 0; j < 16; j++) {
        pc[(size_t)(base + i0 + j)*KK + k] = ac[j];
        ps[(size_t)(base + i0 + j)*KK + k] = as[j];
    }
}

__global__ void k_ared(const float* __restrict__ pc, const float* __restrict__ ps,
                       float* __restrict__ Ac, float* __restrict__ As) {
    int idx = blockIdx.x*256 + threadIdx.x;
    if (idx >= BB*CC*KK) return;
    int b = idx / (CC*KK);
    int r = idx % (CC*KK);
    float sc = 0.f, ss = 0.f;
    for (int ch = 0; ch < PP; ch++) {
        size_t o = ((size_t)(b*PP + ch)*CC)*KK + r;
        sc += pc[o]; ss += ps[o];
    }
    Ac[idx] = sc; As[idx] = ss;
}

// ---- channel mix -> interleaved bf16 A-panel rows {2fc[k], -2fs[k]}, + f0 ----
__global__ void __launch_bounds__(256) k_b(const float* __restrict__ Ac, const float* __restrict__ As_,
                                           const float* __restrict__ wc, const float* __restrict__ wsw,
                                           const float* __restrict__ w0, const float* __restrict__ x0,
                                           short* __restrict__ ApanB, float* __restrict__ f0) {
    int idx = blockIdx.x;
    int b = idx / (CC*2);
    int rem = idx % (CC*2);
    int o = rem >> 1, khalf = rem & 1;
    int tid = threadIdx.x;
    int kl = tid & 63, ig = tid >> 6;
    int k = khalf*64 + kl;
    float fc = 0.f, fs = 0.f;
    for (int ii = 0; ii < 16; ii++) {
        int i = ig*16 + ii;
        float a_c = Ac[(b*CC+i)*KK + k];
        float a_s = As_[(b*CC+i)*KK + k];
        float wcc = wc[((size_t)(i*CC+o))*KK + k];
        float wss = wsw[((size_t)(i*CC+o))*KK + k];
        fc += a_c*wcc + a_s*wss;
        fs += a_c*wss - a_s*wcc;
    }
    __shared__ float rc[256], rs[256];
    __shared__ float f0s[64];
    rc[tid] = fc; rs[tid] = fs;
    if (khalf == 0 && tid < 64) f0s[tid] = x0[b*CC + tid] * w0[tid*CC + o];
    __syncthreads();
    if (ig == 0) {
        fc = rc[kl] + rc[64+kl] + rc[128+kl] + rc[192+kl];
        fs = rs[kl] + rs[64+kl] + rs[128+kl] + rs[192+kl];
        unsigned pk = (unsigned)(unsigned short)f2bf(2.f*fc)
                    | ((unsigned)(unsigned short)f2bf(-2.f*fs) << 16);
        ((unsigned*)ApanB)[((size_t)(b*CC + o))*(KTOT/2) + k] = pk;
    }
    if (khalf == 0 && tid == 0) {
        float acc = 0.f;
        for (int i = 0; i < 64; i++) acc += f0s[i];
        f0[b*CC+o] = acc;
    }
}

__global__ void __launch_bounds__(1024) k_scan(const int* __restrict__ counts,
                                               int* __restrict__ offsets) {
    __shared__ int part[1024];
    int b = blockIdx.x;
    int tid = threadIdx.x;
    int base = tid*16;
    int loc[16]; int s = 0;
    for (int j = 0; j < 16; j++) { loc[j] = counts[b*NN + base + j]; s += loc[j]; }
    part[tid] = s;
    __syncthreads();
    for (int off = 1; off < 1024; off <<= 1) {
        int v = (tid >= off) ? part[tid-off] : 0;
        __syncthreads();
        part[tid] += v;
        __syncthreads();
    }
    int excl = part[tid] - s;
    for (int j = 0; j < 16; j++) {
        offsets[b*NN+base+j] = excl;
        excl += loc[j];
    }
}

// ---- fill bins (atomic-free: rank precomputed in k_pre) ----
__global__ void k_fill(const int* __restrict__ edges, const float* __restrict__ egw,
                       const int* __restrict__ offs, const int* __restrict__ rank,
                       float4* __restrict__ bin4) {
    int idx = blockIdx.x*256 + threadIdx.x;
    if (idx >= BB*EE) return;
    int b = idx / EE;
    int tgt = edges[(size_t)idx*2+0];
    int src = edges[(size_t)idx*2+1];
    const float* __restrict__ ew = &egw[(size_t)idx*3];
    float w0 = ew[0], w1 = ew[1], w2 = ew[2];
    int pos = offs[b*NN+tgt] + rank[idx];
    bin4[(size_t)b*EE + pos] = make_float4(__int_as_float(src), w0, w1, w2);
}

// ---- per-node edge accumulate -> gradfT[b][g][n] ----
#define ECAP 1024
__global__ void __launch_bounds__(256) k_edge(const float* __restrict__ xT,
                                              const int* __restrict__ offsets,
                                              const float4* __restrict__ bin4,
                                              float* __restrict__ gradfT) {
    int blk = blockIdx.x;
    int b = blk / (NN/16);
    int n0 = (blk % (NN/16)) * 16;
    int tid = threadIdx.x;
    int lane = tid & 63;
    int w = tid >> 6;                 // 4 waves, 4 nodes each
    __shared__ float4 ebuf[ECAP];
    __shared__ float gl[16][193];
    __shared__ int soff[17];
    if (tid < 16) soff[tid] = offsets[b*NN + n0 + tid];
    if (tid == 16) soff[16] = (n0 + 16 < NN) ? offsets[b*NN + n0 + 16] : EE;
    __syncthreads();
    int base = soff[0];
    int end  = soff[16];
    const float* __restrict__ xTb = &xT[(size_t)b*NN*CC + lane];

    float a0[4], a1[4], a2[4], s0[4], s1[4], s2[4];
#pragma unroll
    for (int q = 0; q < 4; q++) { a0[q]=a1[q]=a2[q]=0.f; s0[q]=s1[q]=s2[q]=0.f; }

    for (int cs = base; cs < end; cs += ECAP) {
        int ce = min(cs + ECAP, end);
        __syncthreads();
        for (int t = cs + tid; t < ce; t += 256)
            ebuf[t - cs] = bin4[(size_t)b*EE + t];
        __syncthreads();
#pragma unroll
        for (int q = 0; q < 4; q++) {
            int nl = w*4 + q;
            int js = max(soff[nl], cs);
            int je = min(soff[nl+1], ce);
#pragma unroll 4
            for (int j = js; j < je; j++) {
                float4 e = ebuf[j - cs];
                int src = __float_as_int(e.x);
                float xs = xTb[(size_t)src*CC];
                a0[q] = fmaf(xs, e.y, a0[q]);
                a1[q] = fmaf(xs, e.z, a1[q]);
                a2[q] = fmaf(xs, e.w, a2[q]);
                s0[q] += e.y; s1[q] += e.z; s2[q] += e.w;
            }
        }
    }
    __syncthreads();
#pragma unroll
    for (int q = 0; q < 4; q++) {
        int nl = w*4 + q;
        float xtgt = xTb[(size_t)(n0 + nl)*CC];
        gl[nl][lane*3+0] = a0[q] - xtgt*s0[q];
        gl[nl][lane*3+1] = a1[q] - xtgt*s1[q];
        gl[nl][lane*3+2] = a2[q] - xtgt*s2[q];
    }
    __syncthreads();
    for (int t = tid; t < 16*192; t += 256) {
        int g = t >> 4, nl = t & 15;
        gradfT[((size_t)b*192+g)*NN + n0 + nl] = gl[nl][g];
    }
}

// ---- final GEMM on MFMA bf16: out = gelu(Apan^T·B + f0), K=576, tile 64o x 64n ----
// 256 thr = 4 waves; wave w owns o-rows 16w..16w+15 (4 MFMA n-tiles of 16).
// A/B staged bf16 in LDS, [row][k] pitch 72 (2-way-free b128 frag reads).
// c==4 also runs the wx·x MFMA (Ws tile) -> xw; c==5 gates it into the h tile.
#define KCB 64
__global__ void __launch_bounds__(256) k_gemm(const float* __restrict__ x,
                                              const float* __restrict__ nodes,
                                              const float* __restrict__ modes,
                                              const float* __restrict__ geo,
                                              const float* __restrict__ gradfT,
                                              const short* __restrict__ ApanB,
                                              const float* __restrict__ f0,
                                              const float* __restrict__ wx,
                                              const float* __restrict__ gwxT,
                                              float* __restrict__ out) {
    int blk = blockIdx.x;
    int b  = blk >> 8;
    int n0 = (blk & 255) * 64;
    int tid = threadIdx.x;
    int lane = tid & 63;
    int w = tid >> 6;                  // 0..3
    int w16 = w * 16;
    int col  = lane & 15;
    int quad = lane >> 4;              // 0..3
    int quad8 = quad * 8;
    int quad4 = quad * 4;

    __shared__ __align__(16) short As[64*72];   // [o][k] bf16
    __shared__ __align__(16) short Bs[64*72];   // [n][k] bf16
    __shared__ __align__(16) short Ws[64*72];   // wx [i][j] bf16
    __shared__ float ndl[192];
    __shared__ float geo3[192];

    for (int e = tid; e < 4096; e += 256) {
        int i = e >> 6, j = e & 63;
        Ws[i*72 + j] = f2bf(wx[i*64 + j]);
    }
    if (tid < 192) ndl[tid]  = nodes[((size_t)b*NN + n0)*3 + tid];
    if (tid < 192) geo3[tid] = geo[((size_t)b*GG + (tid >> 6))*NN + n0 + (tid & 63)];

    f32x4 acc[4], xwa[4];
    float f0v[4];
#pragma unroll
    for (int r = 0; r < 4; r++) f0v[r] = f0[b*CC + w16 + quad4 + r];
#pragma unroll
    for (int nt = 0; nt < 4; nt++) {
#pragma unroll
        for (int r = 0; r < 4; r++) { acc[nt][r] = f0v[r]; xwa[nt][r] = 0.f; }
    }

    const short* __restrict__ Ab = ApanB + ((size_t)b*CC)*KTOT;

    for (int c = 0; c < 9; c++) {
        __syncthreads();
        // stage A chunk: [o][64k] bf16, 16B vector copies (Apan already bf16)
        for (int e = tid; e < 512; e += 256) {
            int o = e >> 3, seg = e & 7;
            *(uint4*)&As[o*72 + seg*8] =
                *(const uint4*)&Ab[(size_t)o*KTOT + c*64 + seg*8];
        }
        // stage B chunk
        if (c < 4) {
            // 32 {cos,sin} pairs; one trig eval per (kp,n); packed uint write
#pragma unroll
            for (int s = 0; s < 8; s++) {
                int e = tid + s*256;          // 0..2047
                int n = e >> 5, kpl = e & 31;
                int kp = c*32 + kpl;
                float t = ndl[n*3+0]*modes[kp*3+0] + ndl[n*3+1]*modes[kp*3+1]
                        + ndl[n*3+2]*modes[kp*3+2];
                unsigned pk = (unsigned)(unsigned short)f2bf(__cosf(t))
                            | ((unsigned)(unsigned short)f2bf(__sinf(t)) << 16);
                ((unsigned*)Bs)[n*36 + kpl] = pk;
            }
        } else if (c == 5) {
            // h tile from xwa (MFMA D-layout): i = w16+quad4+r, n = nt*16+col
#pragma unroll
            for (int r = 0; r < 4; r++) {
                int i = w16 + quad4 + r;
                float g0 = gwxT[i], g1 = gwxT[64+i], g2 = gwxT[128+i];
#pragma unroll
                for (int nt = 0; nt < 4; nt++) {
                    int n = nt*16 + col;
                    float t = g0*geo3[n] + g1*geo3[64+n] + g2*geo3[128+n];
                    float ssv = t / (1.f + fabsf(t));
                    Bs[n*72 + i] = f2bf(ssv * xwa[nt][r]);
                }
            }
        } else {
            const float* __restrict__ src = (c == 4)
                ? &x[(size_t)b*CC*NN]
                : &gradfT[((size_t)b*192 + (c-6)*64)*NN];
#pragma unroll
            for (int s = 0; s < 16; s++) {
                int e = tid + s*256;
                int r = e >> 6, n = e & 63;
                Bs[n*72 + r] = f2bf(src[(size_t)r*NN + n0 + n]);
            }
        }
        __syncthreads();
        // MFMA: 2 k-steps of 32
        int rowA = (w16 + col) * 72;
#pragma unroll
        for (int ko = 0; ko < 2; ko++) {
            int koff = ko*32 + quad8;
            bf16x8 af = *(bf16x8*)&As[rowA + koff];
            if (c == 4) {
                bf16x8 wf = *(bf16x8*)&Ws[rowA + koff];
#pragma unroll
                for (int nt = 0; nt < 4; nt++) {
                    bf16x8 bfv = *(bf16x8*)&Bs[(nt*16 + col)*72 + koff];
                    acc[nt] = __builtin_amdgcn_mfma_f32_16x16x32_bf16(af, bfv, acc[nt], 0, 0, 0);
                    xwa[nt] = __builtin_amdgcn_mfma_f32_16x16x32_bf16(wf, bfv, xwa[nt], 0, 0, 0);
                }
            } else {
#pragma unroll
                for (int nt = 0; nt < 4; nt++) {
                    bf16x8 bfv = *(bf16x8*)&Bs[(nt*16 + col)*72 + koff];
                    acc[nt] = __builtin_amdgcn_mfma_f32_16x16x32_bf16(af, bfv, acc[nt], 0, 0, 0);
                }
            }
        }
    }
    // epilogue: exact GELU, D-layout scatter (coalesced over col)
#pragma unroll
    for (int nt = 0; nt < 4; nt++) {
#pragma unroll
        for (int r = 0; r < 4; r++) {
            int o = w16 + quad4 + r;
            float v = acc[nt][r];
            float g = 0.5f * v * (1.f + erff(v * 0.70710678118654752f));
            out[((size_t)b*CC + o)*NN + n0 + nt*16 + col] = g;
        }
    }
}

extern "C" void kernel_launch(void* const* d_in, const int* in_sizes, int n_in,
                              void* d_out, int out_size, void* d_ws, size_t ws_size,
                              hipStream_t stream) {
    const float* x      = (const float*)d_in[0];
    const float* nodes  = (const float*)d_in[1];
    const float* nwt    = (const float*)d_in[2];
    const float* geo    = (const float*)d_in[3];
    const int*   edges  = (const int*)d_in[4];
    const float* egw    = (const float*)d_in[5];
    const float* modes  = (const float*)d_in[6];
    const float* wc     = (const float*)d_in[7];
    const float* wsw    = (const float*)d_in[8];
    const float* w0     = (const float*)d_in[9];
    const float* W      = (const float*)d_in[10];
    const float* gw     = (const float*)d_in[11];
    const float* geo_wx = (const float*)d_in[12];
    const float* wx     = (const float*)d_in[13];
    const float* w2     = (const float*)d_in[14];

    float* ws   = (float*)d_ws;
    float* xT   = ws + OFF_XT;
    float* pc   = ws + OFF_PC;
    float* ps   = ws + OFF_PS;
    float* Ac   = ws + OFF_AC;
    float* As_  = ws + OFF_AS;
    float* f0   = ws + OFF_F0;
    float* x0   = ws + OFF_X0;
    int*  counts = (int*)(ws + OFF_CNT);
    int*  offs   = (int*)(ws + OFF_OFFS);
    int*  rank   = (int*)(ws + OFF_RANK);
    float4* bin4 = (float4*)(ws + OFF_BIN4);
    float* gradfT = ws + OFF_GRT;
    short* ApanB  = (short*)(ws + OFF_APAN);
    float* gwxT   = ws + OFF_GWXT;
    float* out  = (float*)d_out;

    hipMemsetAsync(counts, 0, (size_t)(BB*NN)*sizeof(int), stream);

    k_prep <<<48, 256, 0, stream>>>(W, gw, geo_wx, w2, gwxT, ApanB);
    k_pre  <<<BB*(NN/64) + BB*CC + (BB*EE)/256, 256, 0, stream>>>(x, nwt, edges, xT, x0,
                                                                  counts, rank);
    k_a    <<<dim3(BB*PP, 2), 256, 0, stream>>>(xT, nodes, nwt, modes, pc, ps);
    k_ared <<<(BB*CC*KK)/256, 256, 0, stream>>>(pc, ps, Ac, As_);
    k_b    <<<BB*CC*2, 256, 0, stream>>>(Ac, As_, wc, wsw, w0, x0, ApanB, f0);
    k_scan <<<BB, 1024, 0, stream>>>(counts, offs);
    k_fill <<<(BB*EE)/256, 256, 0, stream>>>(edges, egw, offs, rank, bin4);
    k_edge <<<BB*(NN/16), 256, 0, stream>>>(xT, offs, bin4, gradfT);
    k_gemm <<<BB*(NN/64), 256, 0, stream>>>(x, nodes, modes, geo, gradfT, ApanB, f0,
                                            wx, gwxT, out);
}

// Round 12
// 221.733 us; speedup vs baseline: 1.4973x; 1.1589x over previous
//
#include <hip/hip_runtime.h>
#include <hip/hip_fp16.h>
#include <math.h>

#define BB 2
#define CC 64
#define NN 16384
#define DD 3
#define KK 128
#define EE 262144
#define GG 3
#define PP 128           // n-chunks for spectral-forward partials
#define LL (NN/PP)       // 128 n per chunk
#define KTOT 576         // concat K: 256 interleaved cos/sin + 64 x + 64 h + 192 gradf

typedef short bf16x8 __attribute__((ext_vector_type(8)));
typedef float f32x4  __attribute__((ext_vector_type(4)));

__device__ __forceinline__ short f2bf(float f) {
    unsigned u = __float_as_uint(f);
    u += 0x7FFF + ((u >> 16) & 1);          // round-to-nearest-even
    return (short)(u >> 16);
}

// ---- workspace layout (float elements) ----
constexpr size_t OFF_XT   = 0;                                  // xT[b][n][i]
constexpr size_t OFF_PC   = OFF_XT   + (size_t)BB*NN*CC;        // partial A_c
constexpr size_t OFF_PS   = OFF_PC   + (size_t)BB*PP*CC*KK;     // partial A_s
constexpr size_t OFF_BIN4 = OFF_PC;                             // float4 binlist[b][E] (aliases pc/ps)
constexpr size_t OFF_AC   = OFF_PS   + (size_t)BB*PP*CC*KK;     // A_c[b][i][k]
constexpr size_t OFF_AS   = OFF_AC   + (size_t)BB*CC*KK;
constexpr size_t OFF_F0   = OFF_AS   + (size_t)BB*CC*KK;        // f0[b][o]
constexpr size_t OFF_X0   = OFF_F0   + (size_t)BB*CC;           // x0[b][i]
constexpr size_t OFF_CNT  = OFF_X0   + (size_t)BB*CC;           // int counts (zeroed)
constexpr size_t OFF_OFFS = OFF_CNT  + (size_t)BB*NN;           // int offsets
constexpr size_t OFF_RANK = OFF_OFFS + (size_t)BB*NN;           // int rank[b][E]
constexpr size_t OFF_GRT  = OFF_RANK + (size_t)BB*EE;           // gradfT[b][g][n]
constexpr size_t OFF_APAN = OFF_GRT  + (size_t)BB*192*NN;       // bf16 ApanT[b][64 o][576 k]
constexpr size_t OFF_GWXT = OFF_APAN + (size_t)BB*KTOT*CC;      // geo_wx^T [g][i] (fp32)

// ---- small transposes + static A-panel rows (bf16, [o][k]) ----
__global__ void k_prep(const float* __restrict__ W, const float* __restrict__ gw,
                       const float* __restrict__ geo_wx, const float* __restrict__ w2,
                       float* gwxT, short* ApanB) {
    int idx = blockIdx.x*256 + threadIdx.x;
    if (idx < CC*CC) {
        int j = idx>>6, o = idx&63;
        short wv  = f2bf(W[o*CC+j]);
        short w2v = f2bf(w2[o*CC+j]);
        ApanB[((size_t)(0*CC+o))*KTOT + 256 + j] = wv;
        ApanB[((size_t)(1*CC+o))*KTOT + 256 + j] = wv;
        ApanB[((size_t)(0*CC+o))*KTOT + 320 + j] = w2v;
        ApanB[((size_t)(1*CC+o))*KTOT + 320 + j] = w2v;
    }
    if (idx < CC*CC*DD) {
        int g = idx>>6, o = idx&63;
        short gv = f2bf(gw[o*(CC*DD)+g]);
        ApanB[((size_t)(0*CC+o))*KTOT + 384 + g] = gv;
        ApanB[((size_t)(1*CC+o))*KTOT + 384 + g] = gv;
    }
    if (idx < GG*CC) { int g = idx>>6, i = idx&63; gwxT[idx] = geo_wx[i*GG+g]; }
}

// ---- fused pre-pass: transpose x -> xT, x0 reduction, edge-count+rank ----
__global__ void __launch_bounds__(256) k_pre(const float* __restrict__ x,
                                             const float* __restrict__ nwt,
                                             const int* __restrict__ edges,
                                             float* __restrict__ xT,
                                             float* __restrict__ x0,
                                             int* __restrict__ counts,
                                             int* __restrict__ rank) {
    int blk = blockIdx.x;
    int tid = threadIdx.x;
    __shared__ float tile[64][65];
    __shared__ float red[256];
    if (blk < BB*(NN/64)) {
        int b = blk / (NN/64);
        int n0 = (blk % (NN/64)) * 64;
        int c = tid & 63, r4 = tid >> 6;
        for (int rr = 0; rr < 16; rr++) {
            int i = r4*16 + rr;
            tile[i][c] = x[((size_t)b*CC + i)*NN + n0 + c];
        }
        __syncthreads();
        for (int rr = 0; rr < 16; rr++) {
            int nn = r4*16 + rr;
            xT[((size_t)b*NN + n0 + nn)*CC + c] = tile[c][nn];
        }
    } else if (blk < BB*(NN/64) + BB*CC) {
        int bi = blk - BB*(NN/64);
        int b = bi >> 6, i = bi & 63;
        const float4* __restrict__ xr = (const float4*)&x[((size_t)b*CC + i)*NN];
        const float4* __restrict__ wr = (const float4*)&nwt[(size_t)b*NN];
        float s = 0.f;
        for (int t = tid; t < NN/4; t += 256) {
            float4 xv = xr[t];
            float4 wv = wr[t];
            s += xv.x*wv.x + xv.y*wv.y + xv.z*wv.z + xv.w*wv.w;
        }
        red[tid] = s;
        __syncthreads();
        for (int off = 128; off > 0; off >>= 1) {
            if (tid < off) red[tid] += red[tid+off];
            __syncthreads();
        }
        if (tid == 0) x0[b*CC + i] = red[0];
    } else {
        int idx = (blk - (BB*(NN/64) + BB*CC))*256 + tid;
        if (idx < BB*EE) {
            int tgt = edges[(size_t)idx*2 + 0];
            int b = idx / EE;
            rank[idx] = atomicAdd(&counts[b*NN + tgt], 1);
        }
    }
}

// ---- spectral forward partials on MFMA: A_c/A_s[b][i][k] over n-chunks ----
// grid (BB*PP, 2): x = (b, 128-n chunk), y = 64-k half. 256 thr = 4 waves.
// A = bf16 xw[i][n] (x*nw), B = bf16 basis[k][n] (cos / sin), fp32 acc.
// Wave w owns k-subtile 16w..16w+15; loops 4 i-tiles; 4 n-steps of 32.
__global__ void __launch_bounds__(256) k_a(const float* __restrict__ xT,
                                           const float* __restrict__ nodes,
                                           const float* __restrict__ nwt,
                                           const float* __restrict__ modes,
                                           float* __restrict__ pc, float* __restrict__ ps) {
    int bc = blockIdx.x;
    int b = bc / PP, chunk = bc % PP;
    int k0 = blockIdx.y * 64;
    int nbase = chunk * LL;
    int tid = threadIdx.x;
    int lane = tid & 63;
    int w = tid >> 6;
    int col = lane & 15;
    int quad = lane >> 4;

    __shared__ __align__(16) short Axw[64*136];   // [i][n] bf16
    __shared__ __align__(16) short Bc [64*136];   // [k][n] bf16 cos
    __shared__ __align__(16) short Bsn[64*136];   // [k][n] bf16 sin
    __shared__ float ndl[LL*3];

    // phase 0: stage nodes + xw tile
    for (int e = tid; e < LL*3; e += 256) ndl[e] = nodes[((size_t)b*NN + nbase)*3 + e];
#pragma unroll
    for (int s = 0; s < 32; s++) {
        int e = tid + s*256;                 // 8192 = 128 n x 64 i
        int n = e >> 6, i = e & 63;
        float v = xT[((size_t)b*NN + nbase + n)*CC + i] * nwt[b*NN + nbase + n];
        Axw[i*136 + n] = f2bf(v);
    }
    __syncthreads();
    // phase 1: basis tile (one trig eval per (k,n))
#pragma unroll
    for (int s = 0; s < 32; s++) {
        int e = tid + s*256;                 // 8192 = 64 k x 128 n
        int n = e & 127, kl = e >> 7;
        int k = k0 + kl;
        float t = ndl[n*3+0]*modes[k*3+0] + ndl[n*3+1]*modes[k*3+1]
                + ndl[n*3+2]*modes[k*3+2];
        Bc [kl*136 + n] = f2bf(__cosf(t));
        Bsn[kl*136 + n] = f2bf(__sinf(t));
    }
    __syncthreads();

    f32x4 ac[4], as4[4];
#pragma unroll
    for (int it = 0; it < 4; it++)
#pragma unroll
        for (int r = 0; r < 4; r++) { ac[it][r] = 0.f; as4[it][r] = 0.f; }

    int rowB = (w*16 + col)*136;
#pragma unroll
    for (int ns = 0; ns < 4; ns++) {
        int koff = ns*32 + quad*8;
        bf16x8 bcf = *(bf16x8*)&Bc [rowB + koff];
        bf16x8 bsf = *(bf16x8*)&Bsn[rowB + koff];
#pragma unroll
        for (int it = 0; it < 4; it++) {
            bf16x8 af = *(bf16x8*)&Axw[(it*16 + col)*136 + koff];
            ac[it]  = __builtin_amdgcn_mfma_f32_16x16x32_bf16(af, bcf, ac[it], 0, 0, 0);
            as4[it] = __builtin_amdgcn_mfma_f32_16x16x32_bf16(af, bsf, as4[it], 0, 0, 0);
        }
    }
    // write partials: D layout col = k-col, row = quad*4+r = i-within-tile
    int base = (b*PP + chunk)*CC;
    int kw = k0 + w*16 + col;
#pragma unroll
    for (int it = 0; it < 4; it++) {
#pragma unroll
        for (int r = 0; r < 4; r++) {
            int i = it*16 + quad*4 + r;
            pc[(size_t)(base + i)*KK + kw] = ac[it][r];
            ps[(size_t)(base + i)*KK + kw] = as4[it][r];
        }
    }
}

__global__ void k_ared(const float* __restrict__ pc, const float* __restrict__ ps,
                       float* __restrict__ Ac, float* __restrict__ As) {
    int idx = blockIdx.x*256 + threadIdx.x;
    if (idx >= BB*CC*KK) return;
    int b = idx / (CC*KK);
    int r = idx % (CC*KK);
    float sc = 0.f, ss = 0.f;
    for (int ch = 0; ch < PP; ch++) {
        size_t o = ((size_t)(b*PP + ch)*CC)*KK + r;
        sc += pc[o]; ss += ps[o];
    }
    Ac[idx] = sc; As[idx] = ss;
}

// ---- channel mix -> interleaved bf16 A-panel rows {2fc[k], -2fs[k]}, + f0 ----
__global__ void __launch_bounds__(256) k_b(const float* __restrict__ Ac, const float* __restrict__ As_,
                                           const float* __restrict__ wc, const float* __restrict__ wsw,
                                           const float* __restrict__ w0, const float* __restrict__ x0,
                                           short* __restrict__ ApanB, float* __restrict__ f0) {
    int idx = blockIdx.x;
    int b = idx / (CC*2);
    int rem = idx % (CC*2);
    int o = rem >> 1, khalf = rem & 1;
    int tid = threadIdx.x;
    int kl = tid & 63, ig = tid >> 6;
    int k = khalf*64 + kl;
    float fc = 0.f, fs = 0.f;
    for (int ii = 0; ii < 16; ii++) {
        int i = ig*16 + ii;
        float a_c = Ac[(b*CC+i)*KK + k];
        float a_s = As_[(b*CC+i)*KK + k];
        float wcc = wc[((size_t)(i*CC+o))*KK + k];
        float wss = wsw[((size_t)(i*CC+o))*KK + k];
        fc += a_c*wcc + a_s*wss;
        fs += a_c*wss - a_s*wcc;
    }
    __shared__ float rc[256], rs[256];
    __shared__ float f0s[64];
    rc[tid] = fc; rs[tid] = fs;
    if (khalf == 0 && tid < 64) f0s[tid] = x0[b*CC + tid] * w0[tid*CC + o];
    __syncthreads();
    if (ig == 0) {
        fc = rc[kl] + rc[64+kl] + rc[128+kl] + rc[192+kl];
        fs = rs[kl] + rs[64+kl] + rs[128+kl] + rs[192+kl];
        unsigned pk = (unsigned)(unsigned short)f2bf(2.f*fc)
                    | ((unsigned)(unsigned short)f2bf(-2.f*fs) << 16);
        ((unsigned*)ApanB)[((size_t)(b*CC + o))*(KTOT/2) + k] = pk;
    }
    if (khalf == 0 && tid == 0) {
        float acc = 0.f;
        for (int i = 0; i < 64; i++) acc += f0s[i];
        f0[b*CC+o] = acc;
    }
}

__global__ void __launch_bounds__(1024) k_scan(const int* __restrict__ counts,
                                               int* __restrict__ offsets) {
    __shared__ int part[1024];
    int b = blockIdx.x;
    int tid = threadIdx.x;
    int base = tid*16;
    int loc[16]; int s = 0;
    for (int j = 0; j < 16; j++) { loc[j] = counts[b*NN + base + j]; s += loc[j]; }
    part[tid] = s;
    __syncthreads();
    for (int off = 1; off < 1024; off <<= 1) {
        int v = (tid >= off) ? part[tid-off] : 0;
        __syncthreads();
        part[tid] += v;
        __syncthreads();
    }
    int excl = part[tid] - s;
    for (int j = 0; j < 16; j++) {
        offsets[b*NN+base+j] = excl;
        excl += loc[j];
    }
}

// ---- fill bins (atomic-free: rank precomputed in k_pre) ----
__global__ void k_fill(const int* __restrict__ edges, const float* __restrict__ egw,
                       const int* __restrict__ offs, const int* __restrict__ rank,
                       float4* __restrict__ bin4) {
    int idx = blockIdx.x*256 + threadIdx.x;
    if (idx >= BB*EE) return;
    int b = idx / EE;
    int tgt = edges[(size_t)idx*2+0];
    int src = edges[(size_t)idx*2+1];
    const float* __restrict__ ew = &egw[(size_t)idx*3];
    float w0 = ew[0], w1 = ew[1], w2 = ew[2];
    int pos = offs[b*NN+tgt] + rank[idx];
    bin4[(size_t)b*EE + pos] = make_float4(__int_as_float(src), w0, w1, w2);
}

// ---- per-node edge accumulate -> gradfT[b][g][n] ----
#define ECAP 1024
__global__ void __launch_bounds__(256) k_edge(const float* __restrict__ xT,
                                              const int* __restrict__ offsets,
                                              const float4* __restrict__ bin4,
                                              float* __restrict__ gradfT) {
    int blk = blockIdx.x;
    int b = blk / (NN/16);
    int n0 = (blk % (NN/16)) * 16;
    int tid = threadIdx.x;
    int lane = tid & 63;
    int w = tid >> 6;                 // 4 waves, 4 nodes each
    __shared__ float4 ebuf[ECAP];
    __shared__ float gl[16][193];
    __shared__ int soff[17];
    if (tid < 16) soff[tid] = offsets[b*NN + n0 + tid];
    if (tid == 16) soff[16] = (n0 + 16 < NN) ? offsets[b*NN + n0 + 16] : EE;
    __syncthreads();
    int base = soff[0];
    int end  = soff[16];
    const float* __restrict__ xTb = &xT[(size_t)b*NN*CC + lane];

    float a0[4], a1[4], a2[4], s0[4], s1[4], s2[4];
#pragma unroll
    for (int q = 0; q < 4; q++) { a0[q]=a1[q]=a2[q]=0.f; s0[q]=s1[q]=s2[q]=0.f; }

    for (int cs = base; cs < end; cs += ECAP) {
        int ce = min(cs + ECAP, end);
        __syncthreads();
        for (int t = cs + tid; t < ce; t += 256)
            ebuf[t - cs] = bin4[(size_t)b*EE + t];
        __syncthreads();
#pragma unroll
        for (int q = 0; q < 4; q++) {
            int nl = w*4 + q;
            int js = max(soff[nl], cs);
            int je = min(soff[nl+1], ce);
#pragma unroll 4
            for (int j = js; j < je; j++) {
                float4 e = ebuf[j - cs];
                int src = __float_as_int(e.x);
                float xs = xTb[(size_t)src*CC];
                a0[q] = fmaf(xs, e.y, a0[q]);
                a1[q] = fmaf(xs, e.z, a1[q]);
                a2[q] = fmaf(xs, e.w, a2[q]);
                s0[q] += e.y; s1[q] += e.z; s2[q] += e.w;
            }
        }
    }
    __syncthreads();
#pragma unroll
    for (int q = 0; q < 4; q++) {
        int nl = w*4 + q;
        float xtgt = xTb[(size_t)(n0 + nl)*CC];
        gl[nl][lane*3+0] = a0[q] - xtgt*s0[q];
        gl[nl][lane*3+1] = a1[q] - xtgt*s1[q];
        gl[nl][lane*3+2] = a2[q] - xtgt*s2[q];
    }
    __syncthreads();
    for (int t = tid; t < 16*192; t += 256) {
        int g = t >> 4, nl = t & 15;
        gradfT[((size_t)b*192+g)*NN + n0 + nl] = gl[nl][g];
    }
}

// ---- final GEMM on MFMA bf16: out = gelu(Apan^T·B + f0), K=576, tile 64o x 64n ----
#define KCB 64
__global__ void __launch_bounds__(256) k_gemm(const float* __restrict__ x,
                                              const float* __restrict__ nodes,
                                              const float* __restrict__ modes,
                                              const float* __restrict__ geo,
                                              const float* __restrict__ gradfT,
                                              const short* __restrict__ ApanB,
                                              const float* __restrict__ f0,
                                              const float* __restrict__ wx,
                                              const float* __restrict__ gwxT,
                                              float* __restrict__ out) {
    int blk = blockIdx.x;
    int b  = blk >> 8;
    int n0 = (blk & 255) * 64;
    int tid = threadIdx.x;
    int lane = tid & 63;
    int w = tid >> 6;                  // 0..3
    int w16 = w * 16;
    int col  = lane & 15;
    int quad = lane >> 4;              // 0..3
    int quad8 = quad * 8;
    int quad4 = quad * 4;

    __shared__ __align__(16) short As[64*72];   // [o][k] bf16
    __shared__ __align__(16) short Bs[64*72];   // [n][k] bf16
    __shared__ __align__(16) short Ws[64*72];   // wx [i][j] bf16
    __shared__ float ndl[192];
    __shared__ float geo3[192];

    for (int e = tid; e < 4096; e += 256) {
        int i = e >> 6, j = e & 63;
        Ws[i*72 + j] = f2bf(wx[i*64 + j]);
    }
    if (tid < 192) ndl[tid]  = nodes[((size_t)b*NN + n0)*3 + tid];
    if (tid < 192) geo3[tid] = geo[((size_t)b*GG + (tid >> 6))*NN + n0 + (tid & 63)];

    f32x4 acc[4], xwa[4];
    float f0v[4];
#pragma unroll
    for (int r = 0; r < 4; r++) f0v[r] = f0[b*CC + w16 + quad4 + r];
#pragma unroll
    for (int nt = 0; nt < 4; nt++) {
#pragma unroll
        for (int r = 0; r < 4; r++) { acc[nt][r] = f0v[r]; xwa[nt][r] = 0.f; }
    }

    const short* __restrict__ Ab = ApanB + ((size_t)b*CC)*KTOT;

    for (int c = 0; c < 9; c++) {
        __syncthreads();
        for (int e = tid; e < 512; e += 256) {
            int o = e >> 3, seg = e & 7;
            *(uint4*)&As[o*72 + seg*8] =
                *(const uint4*)&Ab[(size_t)o*KTOT + c*64 + seg*8];
        }
        if (c < 4) {
#pragma unroll
            for (int s = 0; s < 8; s++) {
                int e = tid + s*256;
                int n = e >> 5, kpl = e & 31;
                int kp = c*32 + kpl;
                float t = ndl[n*3+0]*modes[kp*3+0] + ndl[n*3+1]*modes[kp*3+1]
                        + ndl[n*3+2]*modes[kp*3+2];
                unsigned pk = (unsigned)(unsigned short)f2bf(__cosf(t))
                            | ((unsigned)(unsigned short)f2bf(__sinf(t)) << 16);
                ((unsigned*)Bs)[n*36 + kpl] = pk;
            }
        } else if (c == 5) {
#pragma unroll
            for (int r = 0; r < 4; r++) {
                int i = w16 + quad4 + r;
                float g0 = gwxT[i], g1 = gwxT[64+i], g2 = gwxT[128+i];
#pragma unroll
                for (int nt = 0; nt < 4; nt++) {
                    int n = nt*16 + col;
                    float t = g0*geo3[n] + g1*geo3[64+n] + g2*geo3[128+n];
                    float ssv = t / (1.f + fabsf(t));
                    Bs[n*72 + i] = f2bf(ssv * xwa[nt][r]);
                }
            }
        } else {
            const float* __restrict__ src = (c == 4)
                ? &x[(size_t)b*CC*NN]
                : &gradfT[((size_t)b*192 + (c-6)*64)*NN];
#pragma unroll
            for (int s = 0; s < 16; s++) {
                int e = tid + s*256;
                int r = e >> 6, n = e & 63;
                Bs[n*72 + r] = f2bf(src[(size_t)r*NN + n0 + n]);
            }
        }
        __syncthreads();
        int rowA = (w16 + col) * 72;
#pragma unroll
        for (int ko = 0; ko < 2; ko++) {
            int koff = ko*32 + quad8;
            bf16x8 af = *(bf16x8*)&As[rowA + koff];
            if (c == 4) {
                bf16x8 wf = *(bf16x8*)&Ws[rowA + koff];
#pragma unroll
                for (int nt = 0; nt < 4; nt++) {
                    bf16x8 bfv = *(bf16x8*)&Bs[(nt*16 + col)*72 + koff];
                    acc[nt] = __builtin_amdgcn_mfma_f32_16x16x32_bf16(af, bfv, acc[nt], 0, 0, 0);
                    xwa[nt] = __builtin_amdgcn_mfma_f32_16x16x32_bf16(wf, bfv, xwa[nt], 0, 0, 0);
                }
            } else {
#pragma unroll
                for (int nt = 0; nt < 4; nt++) {
                    bf16x8 bfv = *(bf16x8*)&Bs[(nt*16 + col)*72 + koff];
                    acc[nt] = __builtin_amdgcn_mfma_f32_16x16x32_bf16(af, bfv, acc[nt], 0, 0, 0);
                }
            }
        }
    }
#pragma unroll
    for (int nt = 0; nt < 4; nt++) {
#pragma unroll
        for (int r = 0; r < 4; r++) {
            int o = w16 + quad4 + r;
            float v = acc[nt][r];
            float g = 0.5f * v * (1.f + erff(v * 0.70710678118654752f));
            out[((size_t)b*CC + o)*NN + n0 + nt*16 + col] = g;
        }
    }
}

extern "C" void kernel_launch(void* const* d_in, const int* in_sizes, int n_in,
                              void* d_out, int out_size, void* d_ws, size_t ws_size,
                              hipStream_t stream) {
    const float* x      = (const float*)d_in[0];
    const float* nodes  = (const float*)d_in[1];
    const float* nwt    = (const float*)d_in[2];
    const float* geo    = (const float*)d_in[3];
    const int*   edges  = (const int*)d_in[4];
    const float* egw    = (const float*)d_in[5];
    const float* modes  = (const float*)d_in[6];
    const float* wc     = (const float*)d_in[7];
    const float* wsw    = (const float*)d_in[8];
    const float* w0     = (const float*)d_in[9];
    const float* W      = (const float*)d_in[10];
    const float* gw     = (const float*)d_in[11];
    const float* geo_wx = (const float*)d_in[12];
    const float* wx     = (const float*)d_in[13];
    const float* w2     = (const float*)d_in[14];

    float* ws   = (float*)d_ws;
    float* xT   = ws + OFF_XT;
    float* pc   = ws + OFF_PC;
    float* ps   = ws + OFF_PS;
    float* Ac   = ws + OFF_AC;
    float* As_  = ws + OFF_AS;
    float* f0   = ws + OFF_F0;
    float* x0   = ws + OFF_X0;
    int*  counts = (int*)(ws + OFF_CNT);
    int*  offs   = (int*)(ws + OFF_OFFS);
    int*  rank   = (int*)(ws + OFF_RANK);
    float4* bin4 = (float4*)(ws + OFF_BIN4);
    float* gradfT = ws + OFF_GRT;
    short* ApanB  = (short*)(ws + OFF_APAN);
    float* gwxT   = ws + OFF_GWXT;
    float* out  = (float*)d_out;

    hipMemsetAsync(counts, 0, (size_t)(BB*NN)*sizeof(int), stream);

    k_prep <<<48, 256, 0, stream>>>(W, gw, geo_wx, w2, gwxT, ApanB);
    k_pre  <<<BB*(NN/64) + BB*CC + (BB*EE)/256, 256, 0, stream>>>(x, nwt, edges, xT, x0,
                                                                  counts, rank);
    k_a    <<<dim3(BB*PP, 2), 256, 0, stream>>>(xT, nodes, nwt, modes, pc, ps);
    k_ared <<<(BB*CC*KK)/256, 256, 0, stream>>>(pc, ps, Ac, As_);
    k_b    <<<BB*CC*2, 256, 0, stream>>>(Ac, As_, wc, wsw, w0, x0, ApanB, f0);
    k_scan <<<BB, 1024, 0, stream>>>(counts, offs);
    k_fill <<<(BB*EE)/256, 256, 0, stream>>>(edges, egw, offs, rank, bin4);
    k_edge <<<BB*(NN/16), 256, 0, stream>>>(xT, offs, bin4, gradfT);
    k_gemm <<<BB*(NN/64), 256, 0, stream>>>(x, nodes, modes, geo, gradfT, ApanB, f0,
                                            wx, gwxT, out);
}

// Round 14
// 216.553 us; speedup vs baseline: 1.5331x; 1.0239x over previous
//
#include <hip/hip_runtime.h>
#include <hip/hip_fp16.h>
#include <math.h>

#define BB 2
#define CC 64
#define NN 16384
#define DD 3
#define KK 128
#define EE 262144
#define GG 3
#define PP 128           // n-chunks for spectral-forward partials
#define LL (NN/PP)       // 128 n per chunk
#define KTOT 576         // concat K: 256 interleaved cos/sin + 64 x + 64 h + 192 gradf

typedef short bf16x8 __attribute__((ext_vector_type(8)));
typedef float f32x4  __attribute__((ext_vector_type(4)));

__device__ __forceinline__ short f2bf(float f) {
    unsigned u = __float_as_uint(f);
    u += 0x7FFF + ((u >> 16) & 1);          // round-to-nearest-even
    return (short)(u >> 16);
}
__device__ __forceinline__ float bf2f(unsigned short u) {
    return __uint_as_float(((unsigned)u) << 16);
}

// ---- workspace layout (float elements) ----
constexpr size_t OFF_XB   = 0;                                  // bf16 xB[b][n][64]
constexpr size_t OFF_XWB  = OFF_XB   + (size_t)BB*NN*32;        // bf16 xwB[b][64 i][NN] (x*nw)
constexpr size_t OFF_PC   = OFF_XWB  + (size_t)BB*NN*32;        // fp32 partial A_c
constexpr size_t OFF_PS   = OFF_PC   + (size_t)BB*PP*CC*KK;     // fp32 partial A_s
constexpr size_t OFF_BIN4 = OFF_PC;                             // float4 binlist[b][E] (aliases pc)
constexpr size_t OFF_AC   = OFF_PS   + (size_t)BB*PP*CC*KK;     // A_c[b][i][k]
constexpr size_t OFF_AS   = OFF_AC   + (size_t)BB*CC*KK;
constexpr size_t OFF_F0   = OFF_AS   + (size_t)BB*CC*KK;        // f0[b][o]
constexpr size_t OFF_X0   = OFF_F0   + (size_t)BB*CC;           // x0[b][i]
constexpr size_t OFF_CNT  = OFF_X0   + (size_t)BB*CC;           // int counts (zeroed)
constexpr size_t OFF_OFFS = OFF_CNT  + (size_t)BB*NN;           // int offsets
constexpr size_t OFF_RANK = OFF_OFFS + (size_t)BB*NN;           // int rank[b][E]
constexpr size_t OFF_GRB  = OFF_RANK + (size_t)BB*EE;           // bf16 gradfB[b][n][192]
constexpr size_t OFF_APAN = OFF_GRB  + (size_t)BB*NN*96;        // bf16 ApanT[b][64 o][576 k]
constexpr size_t OFF_GWXT = OFF_APAN + (size_t)BB*KTOT*CC/2;    // geo_wx^T [g][i] (fp32)

// ---- fused pre-pass ----
// blocks [0,512): transpose x -> xB bf16 [n][i], xwB bf16 [i][n] (x*nw)
// blocks [512,640): x0 reduction; [640,2688): edge count+rank; [2688,2736): weights prep
__global__ void __launch_bounds__(256) k_pre(const float* __restrict__ x,
                                             const float* __restrict__ nwt,
                                             const int* __restrict__ edges,
                                             const float* __restrict__ W,
                                             const float* __restrict__ gw,
                                             const float* __restrict__ geo_wx,
                                             const float* __restrict__ w2,
                                             unsigned short* __restrict__ xB,
                                             unsigned short* __restrict__ xwB,
                                             float* __restrict__ x0,
                                             int* __restrict__ counts,
                                             int* __restrict__ rank,
                                             float* __restrict__ gwxT,
                                             short* __restrict__ ApanB) {
    int blk = blockIdx.x;
    int tid = threadIdx.x;
    __shared__ float tile[64][65];
    __shared__ float red[256];
    if (blk < BB*(NN/64)) {
        int b = blk / (NN/64);
        int n0 = (blk % (NN/64)) * 64;
        int c = tid & 63, r4 = tid >> 6;
        for (int rr = 0; rr < 16; rr++) {
            int i = r4*16 + rr;
            tile[i][c] = x[((size_t)b*CC + i)*NN + n0 + c];
        }
        float nwv = nwt[b*NN + n0 + c];
        __syncthreads();
        for (int rr = 0; rr < 16; rr++) {           // xB[n][i] bf16, lane c = i
            int nn = r4*16 + rr;
            xB[((size_t)b*NN + n0 + nn)*64 + c] = (unsigned short)f2bf(tile[c][nn]);
        }
        for (int rr = 0; rr < 16; rr++) {           // xwB[i][n] bf16, lane c = n
            int i = r4*16 + rr;
            xwB[((size_t)b*CC + i)*NN + n0 + c] = (unsigned short)f2bf(tile[i][c] * nwv);
        }
    } else if (blk < BB*(NN/64) + BB*CC) {
        int bi = blk - BB*(NN/64);
        int b = bi >> 6, i = bi & 63;
        const float4* __restrict__ xr = (const float4*)&x[((size_t)b*CC + i)*NN];
        const float4* __restrict__ wr = (const float4*)&nwt[(size_t)b*NN];
        float s = 0.f;
        for (int t = tid; t < NN/4; t += 256) {
            float4 xv = xr[t];
            float4 wv = wr[t];
            s += xv.x*wv.x + xv.y*wv.y + xv.z*wv.z + xv.w*wv.w;
        }
        red[tid] = s;
        __syncthreads();
        for (int off = 128; off > 0; off >>= 1) {
            if (tid < off) red[tid] += red[tid+off];
            __syncthreads();
        }
        if (tid == 0) x0[b*CC + i] = red[0];
    } else if (blk < BB*(NN/64) + BB*CC + (BB*EE)/256) {
        int idx = (blk - (BB*(NN/64) + BB*CC))*256 + tid;
        if (idx < BB*EE) {
            int tgt = edges[(size_t)idx*2 + 0];
            int b = idx / EE;
            rank[idx] = atomicAdd(&counts[b*NN + tgt], 1);
        }
    } else {
        int idx = (blk - (BB*(NN/64) + BB*CC + (BB*EE)/256))*256 + tid;
        if (idx < CC*CC) {
            int j = idx>>6, o = idx&63;
            short wv  = f2bf(W[o*CC+j]);
            short w2v = f2bf(w2[o*CC+j]);
            ApanB[((size_t)(0*CC+o))*KTOT + 256 + j] = wv;
            ApanB[((size_t)(1*CC+o))*KTOT + 256 + j] = wv;
            ApanB[((size_t)(0*CC+o))*KTOT + 320 + j] = w2v;
            ApanB[((size_t)(1*CC+o))*KTOT + 320 + j] = w2v;
        }
        if (idx < CC*CC*DD) {
            int g = idx>>6, o = idx&63;
            short gv = f2bf(gw[o*(CC*DD)+g]);
            ApanB[((size_t)(0*CC+o))*KTOT + 384 + g] = gv;
            ApanB[((size_t)(1*CC+o))*KTOT + 384 + g] = gv;
        }
        if (idx < GG*CC) { int g = idx>>6, i = idx&63; gwxT[idx] = geo_wx[i*GG+g]; }
    }
}

// ---- spectral forward partials on MFMA: A_c/A_s[b][i][k] over n-chunks ----
__global__ void __launch_bounds__(256) k_a(const unsigned short* __restrict__ xwB,
                                           const float* __restrict__ nodes,
                                           const float* __restrict__ modes,
                                           float* __restrict__ pc, float* __restrict__ ps) {
    int bc = blockIdx.x;
    int b = bc / PP, chunk = bc % PP;
    int k0 = blockIdx.y * 64;
    int nbase = chunk * LL;
    int tid = threadIdx.x;
    int lane = tid & 63;
    int w = tid >> 6;
    int col = lane & 15;
    int quad = lane >> 4;

    __shared__ __align__(16) short Axw[64*136];   // [i][n] bf16
    __shared__ __align__(16) short Bc [64*136];   // [k][n] bf16 cos
    __shared__ __align__(16) short Bsn[64*136];   // [k][n] bf16 sin
    __shared__ float ndl[LL*3];

    // stage nodes + xw tile (vector copies; BUGFIX r13: full 64i x 128n = 1024 uint4)
    for (int e = tid; e < LL*3; e += 256) ndl[e] = nodes[((size_t)b*NN + nbase)*3 + e];
#pragma unroll
    for (int s = 0; s < 4; s++) {
        int e = tid + s*256;                 // 1024 = 64 i x 16 segs (8 bf16 each)
        int i = e >> 4, seg = e & 15;
        *(uint4*)&Axw[i*136 + seg*8] =
            *(const uint4*)&xwB[((size_t)b*CC + i)*NN + nbase + seg*8];
    }
    __syncthreads();
    // basis tile (one trig eval per (k,n))
#pragma unroll
    for (int s = 0; s < 32; s++) {
        int e = tid + s*256;                 // 8192 = 64 k x 128 n
        int n = e & 127, kl = e >> 7;
        int k = k0 + kl;
        float t = ndl[n*3+0]*modes[k*3+0] + ndl[n*3+1]*modes[k*3+1]
                + ndl[n*3+2]*modes[k*3+2];
        Bc [kl*136 + n] = f2bf(__cosf(t));
        Bsn[kl*136 + n] = f2bf(__sinf(t));
    }
    __syncthreads();

    f32x4 ac[4], as4[4];
#pragma unroll
    for (int it = 0; it < 4; it++)
#pragma unroll
        for (int r = 0; r < 4; r++) { ac[it][r] = 0.f; as4[it][r] = 0.f; }

    int rowB = (w*16 + col)*136;
#pragma unroll
    for (int ns = 0; ns < 4; ns++) {
        int koff = ns*32 + quad*8;
        bf16x8 bcf = *(bf16x8*)&Bc [rowB + koff];
        bf16x8 bsf = *(bf16x8*)&Bsn[rowB + koff];
#pragma unroll
        for (int it = 0; it < 4; it++) {
            bf16x8 af = *(bf16x8*)&Axw[(it*16 + col)*136 + koff];
            ac[it]  = __builtin_amdgcn_mfma_f32_16x16x32_bf16(af, bcf, ac[it], 0, 0, 0);
            as4[it] = __builtin_amdgcn_mfma_f32_16x16x32_bf16(af, bsf, as4[it], 0, 0, 0);
        }
    }
    int base = (b*PP + chunk)*CC;
    int kw = k0 + w*16 + col;
#pragma unroll
    for (int it = 0; it < 4; it++) {
#pragma unroll
        for (int r = 0; r < 4; r++) {
            int i = it*16 + quad*4 + r;
            pc[(size_t)(base + i)*KK + kw] = ac[it][r];
            ps[(size_t)(base + i)*KK + kw] = as4[it][r];
        }
    }
}

__global__ void k_ared(const float* __restrict__ pc, const float* __restrict__ ps,
                       float* __restrict__ Ac, float* __restrict__ As) {
    int idx = blockIdx.x*256 + threadIdx.x;
    if (idx >= BB*CC*KK) return;
    int b = idx / (CC*KK);
    int r = idx % (CC*KK);
    float sc = 0.f, ss = 0.f;
    for (int ch = 0; ch < PP; ch++) {
        size_t o = ((size_t)(b*PP + ch)*CC)*KK + r;
        sc += pc[o]; ss += ps[o];
    }
    Ac[idx] = sc; As[idx] = ss;
}

// ---- channel mix -> interleaved bf16 A-panel rows {2fc[k], -2fs[k]}, + f0 ----
__global__ void __launch_bounds__(256) k_b(const float* __restrict__ Ac, const float* __restrict__ As_,
                                           const float* __restrict__ wc, const float* __restrict__ wsw,
                                           const float* __restrict__ w0, const float* __restrict__ x0,
                                           short* __restrict__ ApanB, float* __restrict__ f0) {
    int idx = blockIdx.x;
    int b = idx / (CC*2);
    int rem = idx % (CC*2);
    int o = rem >> 1, khalf = rem & 1;
    int tid = threadIdx.x;
    int kl = tid & 63, ig = tid >> 6;
    int k = khalf*64 + kl;
    float fc = 0.f, fs = 0.f;
    for (int ii = 0; ii < 16; ii++) {
        int i = ig*16 + ii;
        float a_c = Ac[(b*CC+i)*KK + k];
        float a_s = As_[(b*CC+i)*KK + k];
        float wcc = wc[((size_t)(i*CC+o))*KK + k];
        float wss = wsw[((size_t)(i*CC+o))*KK + k];
        fc += a_c*wcc + a_s*wss;
        fs += a_c*wss - a_s*wcc;
    }
    __shared__ float rc[256], rs[256];
    __shared__ float f0s[64];
    rc[tid] = fc; rs[tid] = fs;
    if (khalf == 0 && tid < 64) f0s[tid] = x0[b*CC + tid] * w0[tid*CC + o];
    __syncthreads();
    if (ig == 0) {
        fc = rc[kl] + rc[64+kl] + rc[128+kl] + rc[192+kl];
        fs = rs[kl] + rs[64+kl] + rs[128+kl] + rs[192+kl];
        unsigned pk = (unsigned)(unsigned short)f2bf(2.f*fc)
                    | ((unsigned)(unsigned short)f2bf(-2.f*fs) << 16);
        ((unsigned*)ApanB)[((size_t)(b*CC + o))*(KTOT/2) + k] = pk;
    }
    if (khalf == 0 && tid == 0) {
        float acc = 0.f;
        for (int i = 0; i < 64; i++) acc += f0s[i];
        f0[b*CC+o] = acc;
    }
}

__global__ void __launch_bounds__(1024) k_scan(const int* __restrict__ counts,
                                               int* __restrict__ offsets) {
    __shared__ int part[1024];
    int b = blockIdx.x;
    int tid = threadIdx.x;
    int base = tid*16;
    int loc[16]; int s = 0;
    for (int j = 0; j < 16; j++) { loc[j] = counts[b*NN + base + j]; s += loc[j]; }
    part[tid] = s;
    __syncthreads();
    for (int off = 1; off < 1024; off <<= 1) {
        int v = (tid >= off) ? part[tid-off] : 0;
        __syncthreads();
        part[tid] += v;
        __syncthreads();
    }
    int excl = part[tid] - s;
    for (int j = 0; j < 16; j++) {
        offsets[b*NN+base+j] = excl;
        excl += loc[j];
    }
}

// ---- fill bins (atomic-free: rank precomputed in k_pre) ----
__global__ void k_fill(const int* __restrict__ edges, const float* __restrict__ egw,
                       const int* __restrict__ offs, const int* __restrict__ rank,
                       float4* __restrict__ bin4) {
    int idx = blockIdx.x*256 + threadIdx.x;
    if (idx >= BB*EE) return;
    int b = idx / EE;
    int tgt = edges[(size_t)idx*2+0];
    int src = edges[(size_t)idx*2+1];
    const float* __restrict__ ew = &egw[(size_t)idx*3];
    float w0 = ew[0], w1 = ew[1], w2 = ew[2];
    int pos = offs[b*NN+tgt] + rank[idx];
    bin4[(size_t)b*EE + pos] = make_float4(__int_as_float(src), w0, w1, w2);
}

// ---- per-node edge accumulate -> gradfB bf16 [b][n][192] ----
#define ECAP 1024
__global__ void __launch_bounds__(256) k_edge(const unsigned short* __restrict__ xB,
                                              const int* __restrict__ offsets,
                                              const float4* __restrict__ bin4,
                                              unsigned short* __restrict__ gradfB) {
    int blk = blockIdx.x;
    int b = blk / (NN/16);
    int n0 = (blk % (NN/16)) * 16;
    int tid = threadIdx.x;
    int lane = tid & 63;
    int w = tid >> 6;                 // 4 waves, 4 nodes each
    __shared__ float4 ebuf[ECAP];
    __shared__ float gl[16][193];
    __shared__ int soff[17];
    if (tid < 16) soff[tid] = offsets[b*NN + n0 + tid];
    if (tid == 16) soff[16] = (n0 + 16 < NN) ? offsets[b*NN + n0 + 16] : EE;
    __syncthreads();
    int base = soff[0];
    int end  = soff[16];
    const unsigned short* __restrict__ xBb = xB + (size_t)b*NN*64 + lane;

    float a0[4], a1[4], a2[4], s0[4], s1[4], s2[4];
#pragma unroll
    for (int q = 0; q < 4; q++) { a0[q]=a1[q]=a2[q]=0.f; s0[q]=s1[q]=s2[q]=0.f; }

    for (int cs = base; cs < end; cs += ECAP) {
        int ce = min(cs + ECAP, end);
        __syncthreads();
        for (int t = cs + tid; t < ce; t += 256)
            ebuf[t - cs] = bin4[(size_t)b*EE + t];
        __syncthreads();
#pragma unroll
        for (int q = 0; q < 4; q++) {
            int nl = w*4 + q;
            int js = max(soff[nl], cs);
            int je = min(soff[nl+1], ce);
#pragma unroll 4
            for (int j = js; j < je; j++) {
                float4 e = ebuf[j - cs];
                int src = __float_as_int(e.x);
                float xs = bf2f(xBb[(size_t)src*64]);
                a0[q] = fmaf(xs, e.y, a0[q]);
                a1[q] = fmaf(xs, e.z, a1[q]);
                a2[q] = fmaf(xs, e.w, a2[q]);
                s0[q] += e.y; s1[q] += e.z; s2[q] += e.w;
            }
        }
    }
    __syncthreads();
#pragma unroll
    for (int q = 0; q < 4; q++) {
        int nl = w*4 + q;
        float xtgt = bf2f(xBb[(size_t)(n0 + nl)*64]);
        gl[nl][lane*3+0] = a0[q] - xtgt*s0[q];
        gl[nl][lane*3+1] = a1[q] - xtgt*s1[q];
        gl[nl][lane*3+2] = a2[q] - xtgt*s2[q];
    }
    __syncthreads();
    for (int t = tid; t < 16*192; t += 256) {
        int nl = t / 192, g = t % 192;
        gradfB[((size_t)(b*NN + n0 + nl))*192 + g] = (unsigned short)f2bf(gl[nl][g]);
    }
}

// ---- final GEMM on MFMA bf16: out = gelu(Apan^T·B + f0), K=576, tile 64o x 64n ----
__global__ void __launch_bounds__(256) k_gemm(const unsigned short* __restrict__ xB,
                                              const float* __restrict__ nodes,
                                              const float* __restrict__ modes,
                                              const float* __restrict__ geo,
                                              const unsigned short* __restrict__ gradfB,
                                              const short* __restrict__ ApanB,
                                              const float* __restrict__ f0,
                                              const float* __restrict__ wx,
                                              const float* __restrict__ gwxT,
                                              float* __restrict__ out) {
    int blk = blockIdx.x;
    int b  = blk >> 8;
    int n0 = (blk & 255) * 64;
    int tid = threadIdx.x;
    int lane = tid & 63;
    int w = tid >> 6;                  // 0..3
    int w16 = w * 16;
    int col  = lane & 15;
    int quad = lane >> 4;              // 0..3
    int quad8 = quad * 8;
    int quad4 = quad * 4;

    __shared__ __align__(16) short As[64*72];   // [o][k] bf16
    __shared__ __align__(16) short Bs[64*72];   // [n][k] bf16
    __shared__ __align__(16) short Ws[64*72];   // wx [i][j] bf16
    __shared__ float ndl[192];
    __shared__ float geo3[192];

    for (int e = tid; e < 4096; e += 256) {
        int i = e >> 6, j = e & 63;
        Ws[i*72 + j] = f2bf(wx[i*64 + j]);
    }
    if (tid < 192) ndl[tid]  = nodes[((size_t)b*NN + n0)*3 + tid];
    if (tid < 192) geo3[tid] = geo[((size_t)b*GG + (tid >> 6))*NN + n0 + (tid & 63)];

    f32x4 acc[4], xwa[4];
    float f0v[4];
#pragma unroll
    for (int r = 0; r < 4; r++) f0v[r] = f0[b*CC + w16 + quad4 + r];
#pragma unroll
    for (int nt = 0; nt < 4; nt++) {
#pragma unroll
        for (int r = 0; r < 4; r++) { acc[nt][r] = f0v[r]; xwa[nt][r] = 0.f; }
    }

    const short* __restrict__ Ab = ApanB + ((size_t)b*CC)*KTOT;

    for (int c = 0; c < 9; c++) {
        __syncthreads();
        // A chunk: 16B vector copies
        for (int e = tid; e < 512; e += 256) {
            int o = e >> 3, seg = e & 7;
            *(uint4*)&As[o*72 + seg*8] =
                *(const uint4*)&Ab[(size_t)o*KTOT + c*64 + seg*8];
        }
        // B chunk
        if (c < 4) {
#pragma unroll
            for (int s = 0; s < 8; s++) {
                int e = tid + s*256;
                int n = e >> 5, kpl = e & 31;
                int kp = c*32 + kpl;
                float t = ndl[n*3+0]*modes[kp*3+0] + ndl[n*3+1]*modes[kp*3+1]
                        + ndl[n*3+2]*modes[kp*3+2];
                unsigned pk = (unsigned)(unsigned short)f2bf(__cosf(t))
                            | ((unsigned)(unsigned short)f2bf(__sinf(t)) << 16);
                ((unsigned*)Bs)[n*36 + kpl] = pk;
            }
        } else if (c == 4) {
            // x tile: vector copy from bf16 xB[n][i]
            for (int e = tid; e < 512; e += 256) {
                int n = e >> 3, seg = e & 7;
                *(uint4*)&Bs[n*72 + seg*8] =
                    *(const uint4*)&xB[((size_t)(b*NN + n0 + n))*64 + seg*8];
            }
        } else if (c == 5) {
            // h tile from xwa (MFMA D-layout)
#pragma unroll
            for (int r = 0; r < 4; r++) {
                int i = w16 + quad4 + r;
                float g0 = gwxT[i], g1 = gwxT[64+i], g2 = gwxT[128+i];
#pragma unroll
                for (int nt = 0; nt < 4; nt++) {
                    int n = nt*16 + col;
                    float t = g0*geo3[n] + g1*geo3[64+n] + g2*geo3[128+n];
                    float ssv = t / (1.f + fabsf(t));
                    Bs[n*72 + i] = f2bf(ssv * xwa[nt][r]);
                }
            }
        } else {
            // gradf tile: vector copy from bf16 gradfB[n][192]
            const unsigned short* __restrict__ src = gradfB + (size_t)(c-6)*64;
            for (int e = tid; e < 512; e += 256) {
                int n = e >> 3, seg = e & 7;
                *(uint4*)&Bs[n*72 + seg*8] =
                    *(const uint4*)&src[((size_t)(b*NN + n0 + n))*192 + seg*8];
            }
        }
        __syncthreads();
        int rowA = (w16 + col) * 72;
#pragma unroll
        for (int ko = 0; ko < 2; ko++) {
            int koff = ko*32 + quad8;
            bf16x8 af = *(bf16x8*)&As[rowA + koff];
            if (c == 4) {
                bf16x8 wf = *(bf16x8*)&Ws[rowA + koff];
#pragma unroll
                for (int nt = 0; nt < 4; nt++) {
                    bf16x8 bfv = *(bf16x8*)&Bs[(nt*16 + col)*72 + koff];
                    acc[nt] = __builtin_amdgcn_mfma_f32_16x16x32_bf16(af, bfv, acc[nt], 0, 0, 0);
                    xwa[nt] = __builtin_amdgcn_mfma_f32_16x16x32_bf16(wf, bfv, xwa[nt], 0, 0, 0);
                }
            } else {
#pragma unroll
                for (int nt = 0; nt < 4; nt++) {
                    bf16x8 bfv = *(bf16x8*)&Bs[(nt*16 + col)*72 + koff];
                    acc[nt] = __builtin_amdgcn_mfma_f32_16x16x32_bf16(af, bfv, acc[nt], 0, 0, 0);
                }
            }
        }
    }
#pragma unroll
    for (int nt = 0; nt < 4; nt++) {
#pragma unroll
        for (int r = 0; r < 4; r++) {
            int o = w16 + quad4 + r;
            float v = acc[nt][r];
            float g = 0.5f * v * (1.f + erff(v * 0.70710678118654752f));
            out[((size_t)b*CC + o)*NN + n0 + nt*16 + col] = g;
        }
    }
}

extern "C" void kernel_launch(void* const* d_in, const int* in_sizes, int n_in,
                              void* d_out, int out_size, void* d_ws, size_t ws_size,
                              hipStream_t stream) {
    const float* x      = (const float*)d_in[0];
    const float* nodes  = (const float*)d_in[1];
    const float* nwt    = (const float*)d_in[2];
    const float* geo    = (const float*)d_in[3];
    const int*   edges  = (const int*)d_in[4];
    const float* egw    = (const float*)d_in[5];
    const float* modes  = (const float*)d_in[6];
    const float* wc     = (const float*)d_in[7];
    const float* wsw    = (const float*)d_in[8];
    const float* w0     = (const float*)d_in[9];
    const float* W      = (const float*)d_in[10];
    const float* gw     = (const float*)d_in[11];
    const float* geo_wx = (const float*)d_in[12];
    const float* wx     = (const float*)d_in[13];
    const float* w2     = (const float*)d_in[14];

    float* ws   = (float*)d_ws;
    unsigned short* xB  = (unsigned short*)(ws + OFF_XB);
    unsigned short* xwB = (unsigned short*)(ws + OFF_XWB);
    float* pc   = ws + OFF_PC;
    float* ps   = ws + OFF_PS;
    float* Ac   = ws + OFF_AC;
    float* As_  = ws + OFF_AS;
    float* f0   = ws + OFF_F0;
    float* x0   = ws + OFF_X0;
    int*  counts = (int*)(ws + OFF_CNT);
    int*  offs   = (int*)(ws + OFF_OFFS);
    int*  rank   = (int*)(ws + OFF_RANK);
    float4* bin4 = (float4*)(ws + OFF_BIN4);
    unsigned short* gradfB = (unsigned short*)(ws + OFF_GRB);
    short* ApanB  = (short*)(ws + OFF_APAN);
    float* gwxT   = ws + OFF_GWXT;
    float* out  = (float*)d_out;

    hipMemsetAsync(counts, 0, (size_t)(BB*NN)*sizeof(int), stream);

    int npre = BB*(NN/64) + BB*CC + (BB*EE)/256 + 48;
    k_pre  <<<npre, 256, 0, stream>>>(x, nwt, edges, W, gw, geo_wx, w2,
                                      xB, xwB, x0, counts, rank, gwxT, ApanB);
    k_a    <<<dim3(BB*PP, 2), 256, 0, stream>>>(xwB, nodes, modes, pc, ps);
    k_ared <<<(BB*CC*KK)/256, 256, 0, stream>>>(pc, ps, Ac, As_);
    k_b    <<<BB*CC*2, 256, 0, stream>>>(Ac, As_, wc, wsw, w0, x0, ApanB, f0);
    k_scan <<<BB, 1024, 0, stream>>>(counts, offs);
    k_fill <<<(BB*EE)/256, 256, 0, stream>>>(edges, egw, offs, rank, bin4);
    k_edge <<<BB*(NN/16), 256, 0, stream>>>(xB, offs, bin4, gradfB);
    k_gemm <<<BB*(NN/64), 256, 0, stream>>>(xB, nodes, modes, geo, gradfB, ApanB, f0,
                                            wx, gwxT, out);
}